// Round 1
// baseline (547.933 us; speedup 1.0000x reference)
//
#include <hip/hip_runtime.h>
#include <cstdint>

typedef __bf16 bf16x8 __attribute__((ext_vector_type(8)));
typedef float f32x4 __attribute__((ext_vector_type(4)));
typedef unsigned short u16;
typedef unsigned int u32;
typedef unsigned long long u64;

#define B_N 8
#define T_N 2048
#define D_N 512
#define TAU 5.0f

__device__ __forceinline__ u16 f2bf(float x) {
  __bf16 h = (__bf16)x;
  return __builtin_bit_cast(u16, h);
}

// ---------------- k0: per-row inverse L2 norms for pred and text ----------------
__global__ void knorm(const float* __restrict__ pred, const float* __restrict__ text,
                      float* __restrict__ invP, float* __restrict__ invE) {
  int wid = threadIdx.x >> 6, lane = threadIdx.x & 63;
  int row = blockIdx.x * 4 + wid;              // 0..2*B*T-1
  const float* src = (row < B_N * T_N) ? pred : text;
  int r = row & (B_N * T_N - 1);
  const float4* p = (const float4*)(src + (size_t)r * D_N);
  float4 a = p[lane * 2];
  float4 bb = p[lane * 2 + 1];
  float s = a.x * a.x + a.y * a.y + a.z * a.z + a.w * a.w
          + bb.x * bb.x + bb.y * bb.y + bb.z * bb.z + bb.w * bb.w;
#pragma unroll
  for (int m = 32; m >= 1; m >>= 1) s += __shfl_xor(s, m);
  if (lane == 0) {
    float inv = 1.0f / fmaxf(sqrtf(s), 1e-12f);
    (row < B_N * T_N ? invP : invE)[r] = inv;
  }
}

// ---------------- k1: normalized E as bf16, row-major and transposed ----------------
__global__ void kprep(const float* __restrict__ text, const float* __restrict__ invE,
                      u16* __restrict__ Ebf, u16* __restrict__ Etb) {
  __shared__ u16 tile[64][72];
  int b = blockIdx.z, t0 = blockIdx.y * 64, d0 = blockIdx.x * 64;
  int rr = threadIdx.x >> 2, cg = threadIdx.x & 3;
  const float* src = text + ((size_t)(b * T_N) + t0 + rr) * D_N + d0 + cg * 16;
  float inv = invE[b * T_N + t0 + rr];
  u16 v[16];
#pragma unroll
  for (int j = 0; j < 4; ++j) {
    float4 f = *(const float4*)(src + j * 4);
    v[j * 4 + 0] = f2bf(f.x * inv);
    v[j * 4 + 1] = f2bf(f.y * inv);
    v[j * 4 + 2] = f2bf(f.z * inv);
    v[j * 4 + 3] = f2bf(f.w * inv);
  }
  u32 pk[8];
#pragma unroll
  for (int j = 0; j < 8; ++j) pk[j] = (u32)v[2 * j] | ((u32)v[2 * j + 1] << 16);
  u16* dst = Ebf + ((size_t)(b * T_N) + t0 + rr) * D_N + d0 + cg * 16;
  ((uint4*)dst)[0] = make_uint4(pk[0], pk[1], pk[2], pk[3]);
  ((uint4*)dst)[1] = make_uint4(pk[4], pk[5], pk[6], pk[7]);
#pragma unroll
  for (int j = 0; j < 16; ++j) tile[rr][cg * 16 + j] = v[j];
  __syncthreads();
  u16 w[16];
#pragma unroll
  for (int j = 0; j < 16; ++j) w[j] = tile[cg * 16 + j][rr];
#pragma unroll
  for (int j = 0; j < 8; ++j) pk[j] = (u32)w[2 * j] | ((u32)w[2 * j + 1] << 16);
  u16* dt = Etb + ((size_t)(b * D_N) + d0 + rr) * T_N + t0 + cg * 16;
  ((uint4*)dt)[0] = make_uint4(pk[0], pk[1], pk[2], pk[3]);
  ((uint4*)dt)[1] = make_uint4(pk[4], pk[5], pk[6], pk[7]);
}

// ---------------- k2: fused flash attention + cosine row loss ----------------
__launch_bounds__(256, 1)
__global__ void kflash(const float* __restrict__ pred, const float* __restrict__ invP,
                       const u16* __restrict__ Ebf, const u16* __restrict__ Etb,
                       const int* __restrict__ mask, float* __restrict__ rowloss,
                       float* __restrict__ flags) {
  int b = blockIdx.x >> 5, rb = blockIdx.x & 31;
  int wid = threadIdx.x >> 6, lane = threadIdx.x & 63;
  int g = lane >> 4, c = lane & 15;
  int row0 = rb * 64 + wid * 16;

  __shared__ u64 mbits[32];
  __shared__ __align__(16) u16 pbuf[4][16][40];  // per-wave 16x32 P-weights (+pad)

  for (int chunk = wid; chunk < 32; chunk += 4) {
    int col = chunk * 64 + lane;
    u64 bal = __ballot(mask[b * T_N + col] == 0);  // True mask = PAD, valid = (mask==0)
    if (lane == 0) mbits[chunk] = bal;
  }
  __syncthreads();
  u64 anyv = 0;
#pragma unroll
  for (int i = 0; i < 32; ++i) anyv |= mbits[i];
  if (rb == 0 && threadIdx.x == 0) flags[b] = (anyv != 0ULL) ? 1.f : 0.f;
  if (anyv == 0ULL) {
    if (threadIdx.x < 64) rowloss[b * T_N + rb * 64 + threadIdx.x] = 0.f;
    return;
  }

  // P fragments: normalize on the fly, 16 rows per wave resident in registers.
  bf16x8 pf[16];
  {
    int prow = row0 + c;
    const float* pr = pred + ((size_t)(b * T_N) + prow) * D_N;
    float inv = invP[b * T_N + prow];
#pragma unroll
    for (int kk = 0; kk < 16; ++kk) {
      float4 v0 = *(const float4*)(pr + kk * 32 + g * 8);
      float4 v1 = *(const float4*)(pr + kk * 32 + g * 8 + 4);
      bf16x8 f;
      f[0] = (__bf16)(v0.x * inv); f[1] = (__bf16)(v0.y * inv);
      f[2] = (__bf16)(v0.z * inv); f[3] = (__bf16)(v0.w * inv);
      f[4] = (__bf16)(v1.x * inv); f[5] = (__bf16)(v1.y * inv);
      f[6] = (__bf16)(v1.z * inv); f[7] = (__bf16)(v1.w * inv);
      pf[kk] = f;
    }
  }

  f32x4 zero = {0.f, 0.f, 0.f, 0.f};
  f32x4 eh[32];
#pragma unroll
  for (int n = 0; n < 32; ++n) eh[n] = zero;
  float lsum[4] = {0.f, 0.f, 0.f, 0.f};
  float mrun[4] = {-3e38f, -3e38f, -3e38f, -3e38f};

  const u16* Eb = Ebf + (size_t)b * T_N * D_N;
  const u16* Et = Etb + (size_t)b * D_N * T_N;

#pragma unroll 1
  for (int ci = 0; ci < T_N / 32; ++ci) {
    int c0 = ci * 32;
    f32x4 s0 = zero, s1 = zero;
    const u16* e0 = Eb + (size_t)(c0 + c) * D_N + g * 8;
#pragma unroll
    for (int kk = 0; kk < 16; ++kk) {
      bf16x8 b0 = *(const bf16x8*)(e0 + kk * 32);
      bf16x8 b1 = *(const bf16x8*)(e0 + 16 * D_N + kk * 32);
      s0 = __builtin_amdgcn_mfma_f32_16x16x32_bf16(pf[kk], b0, s0, 0, 0, 0);
      s1 = __builtin_amdgcn_mfma_f32_16x16x32_bf16(pf[kk], b1, s1, 0, 0, 0);
    }
    int col0 = c0 + c;
    bool v0 = (mbits[col0 >> 6] >> (col0 & 63)) & 1ULL;
    bool v1 = (mbits[(col0 + 16) >> 6] >> ((col0 + 16) & 63)) & 1ULL;
    float x0[4], x1[4], tm[4];
    bool need = false;
#pragma unroll
    for (int r = 0; r < 4; ++r) {
      x0[r] = v0 ? TAU * s0[r] : -1e30f;
      x1[r] = v1 ? TAU * s1[r] : -1e30f;
      float t = fmaxf(x0[r], x1[r]);
      t = fmaxf(t, __shfl_xor(t, 1));
      t = fmaxf(t, __shfl_xor(t, 2));
      t = fmaxf(t, __shfl_xor(t, 4));
      t = fmaxf(t, __shfl_xor(t, 8));
      tm[r] = t;
      need = need || (t > mrun[r] + 8.f);
    }
    if (__any(need)) {  // defer-max: rescale only when the running max grows >8
      float sc[4];
#pragma unroll
      for (int r = 0; r < 4; ++r) {
        float nm = fmaxf(mrun[r], tm[r]);
        sc[r] = __expf(mrun[r] - nm);
        mrun[r] = nm;
        lsum[r] *= sc[r];
      }
#pragma unroll
      for (int n = 0; n < 32; ++n) {
        eh[n][0] *= sc[0]; eh[n][1] *= sc[1];
        eh[n][2] *= sc[2]; eh[n][3] *= sc[3];
      }
    }
#pragma unroll
    for (int r = 0; r < 4; ++r) {
      float p0 = v0 ? __expf(x0[r] - mrun[r]) : 0.f;
      float p1 = v1 ? __expf(x1[r] - mrun[r]) : 0.f;
      lsum[r] += p0 + p1;
      pbuf[wid][g * 4 + r][c] = f2bf(p0);       // C-layout -> A-layout bounce
      pbuf[wid][g * 4 + r][16 + c] = f2bf(p1);
    }
    bf16x8 af = *(const bf16x8*)&pbuf[wid][c][g * 8];
    const u16* et = Et + (size_t)c * T_N + c0 + g * 8;
#pragma unroll
    for (int n = 0; n < 32; ++n) {
      bf16x8 bv = *(const bf16x8*)(et + (size_t)(n * 16) * T_N);
      eh[n] = __builtin_amdgcn_mfma_f32_16x16x32_bf16(af, bv, eh[n], 0, 0, 0);
    }
  }

  // epilogue: cos per row; cos = dot(P,acc) / max(|acc|, 1e-8*l)  (l cancels otherwise)
#pragma unroll
  for (int r = 0; r < 4; ++r) {
    float t = lsum[r];
    t += __shfl_xor(t, 1); t += __shfl_xor(t, 2);
    t += __shfl_xor(t, 4); t += __shfl_xor(t, 8);
    lsum[r] = t;
  }
  float out_dot[4], out_en2[4];
#pragma unroll
  for (int r = 0; r < 4; ++r) {
    int prow = row0 + g * 4 + r;
    const float* pr = pred + ((size_t)(b * T_N) + prow) * D_N;
    float inv = invP[b * T_N + prow];
    float d = 0.f, e2 = 0.f;
#pragma unroll
    for (int n = 0; n < 32; ++n) {
      float ev = eh[n][r];
      d += ev * (pr[n * 16 + c] * inv);
      e2 += ev * ev;
    }
    d += __shfl_xor(d, 1); d += __shfl_xor(d, 2);
    d += __shfl_xor(d, 4); d += __shfl_xor(d, 8);
    e2 += __shfl_xor(e2, 1); e2 += __shfl_xor(e2, 2);
    e2 += __shfl_xor(e2, 4); e2 += __shfl_xor(e2, 8);
    out_dot[r] = d; out_en2[r] = e2;
  }
  if (c == 0) {
#pragma unroll
    for (int r = 0; r < 4; ++r) {
      int prow = row0 + g * 4 + r;
      float denom = fmaxf(sqrtf(out_en2[r]), 1e-8f * lsum[r]);
      float cosv = out_dot[r] / denom;
      rowloss[b * T_N + prow] = 1.f - cosv;
    }
  }
}

// ---------------- k3: deterministic final reduction ----------------
__global__ void kreduce(const float* __restrict__ rowloss, const float* __restrict__ flags,
                        float* __restrict__ out) {
  __shared__ float sm[256];
  float s = 0.f;
  for (int i = threadIdx.x; i < B_N * T_N; i += 256) s += rowloss[i];
  sm[threadIdx.x] = s;
  __syncthreads();
#pragma unroll
  for (int st = 128; st >= 1; st >>= 1) {
    if ((int)threadIdx.x < st) sm[threadIdx.x] += sm[threadIdx.x + st];
    __syncthreads();
  }
  if (threadIdx.x == 0) {
    float cnt = 0.f;
    for (int i = 0; i < B_N; ++i) cnt += flags[i];
    cnt *= (float)T_N;
    float loss = (cnt > 0.f) ? sm[0] / fmaxf(cnt, 1.f) : 0.f;
    out[0] = loss;
    out[1] = (cnt > 0.f) ? 1.f - loss : 0.f;
  }
}

extern "C" void kernel_launch(void* const* d_in, const int* in_sizes, int n_in,
                              void* d_out, int out_size, void* d_ws, size_t ws_size,
                              hipStream_t stream) {
  const float* pred = (const float*)d_in[0];
  const float* text = (const float*)d_in[1];
  const int* mask = (const int*)d_in[2];
  char* ws = (char*)d_ws;
  const size_t EB = (size_t)B_N * T_N * D_N * 2;  // bytes of one bf16 tensor
  u16* Ebf = (u16*)ws;
  u16* Etb = (u16*)(ws + EB);
  float* invP = (float*)(ws + 2 * EB);
  float* invE = (float*)(ws + 2 * EB + 65536);
  float* rowloss = (float*)(ws + 2 * EB + 131072);
  float* flags = (float*)(ws + 2 * EB + 196608);
  float* out = (float*)d_out;

  knorm<<<dim3(2 * B_N * T_N / 4), dim3(256), 0, stream>>>(pred, text, invP, invE);
  kprep<<<dim3(D_N / 64, T_N / 64, B_N), dim3(256), 0, stream>>>(text, invE, Ebf, Etb);
  kflash<<<dim3(B_N * T_N / 64), dim3(256), 0, stream>>>(pred, invP, Ebf, Etb, mask, rowloss, flags);
  kreduce<<<dim3(1), dim3(256), 0, stream>>>(rowloss, flags, out);
}

// Round 2
// 241.132 us; speedup vs baseline: 2.2723x; 2.2723x over previous
//
#include <hip/hip_runtime.h>
#include <cstdint>

typedef __bf16 bf16x8 __attribute__((ext_vector_type(8)));
typedef float f32x4 __attribute__((ext_vector_type(4)));
typedef unsigned short u16;
typedef unsigned int u32;
typedef unsigned long long u64;

#define B_N 8
#define T_N 2048
#define D_N 512
#define TAU 5.0f

__device__ __forceinline__ u16 f2bf(float x) {
  __bf16 h = (__bf16)x;
  return __builtin_bit_cast(u16, h);
}

__device__ __forceinline__ void gload_lds16(const u16* g, u16* l) {
  __builtin_amdgcn_global_load_lds(
      (const __attribute__((address_space(1))) u32*)g,
      (__attribute__((address_space(3))) u32*)l, 16, 0, 0);
}

// ---------------- k0: per-row inverse L2 norms for pred and text ----------------
__global__ void knorm(const float* __restrict__ pred, const float* __restrict__ text,
                      float* __restrict__ invP, float* __restrict__ invE) {
  int wid = threadIdx.x >> 6, lane = threadIdx.x & 63;
  int row = blockIdx.x * 4 + wid;              // 0..2*B*T-1
  const float* src = (row < B_N * T_N) ? pred : text;
  int r = row & (B_N * T_N - 1);
  const float4* p = (const float4*)(src + (size_t)r * D_N);
  float4 a = p[lane * 2];
  float4 bb = p[lane * 2 + 1];
  float s = a.x * a.x + a.y * a.y + a.z * a.z + a.w * a.w
          + bb.x * bb.x + bb.y * bb.y + bb.z * bb.z + bb.w * bb.w;
#pragma unroll
  for (int m = 32; m >= 1; m >>= 1) s += __shfl_xor(s, m);
  if (lane == 0) {
    float inv = 1.0f / fmaxf(sqrtf(s), 1e-12f);
    (row < B_N * T_N ? invP : invE)[r] = inv;
  }
}

// ---------------- k1: normalized E as bf16, row-major and transposed ----------------
__global__ void kprep(const float* __restrict__ text, const float* __restrict__ invE,
                      u16* __restrict__ Ebf, u16* __restrict__ Etb) {
  __shared__ u16 tile[64][72];
  int b = blockIdx.z, t0 = blockIdx.y * 64, d0 = blockIdx.x * 64;
  int rr = threadIdx.x >> 2, cg = threadIdx.x & 3;
  const float* src = text + ((size_t)(b * T_N) + t0 + rr) * D_N + d0 + cg * 16;
  float inv = invE[b * T_N + t0 + rr];
  u16 v[16];
#pragma unroll
  for (int j = 0; j < 4; ++j) {
    float4 f = *(const float4*)(src + j * 4);
    v[j * 4 + 0] = f2bf(f.x * inv);
    v[j * 4 + 1] = f2bf(f.y * inv);
    v[j * 4 + 2] = f2bf(f.z * inv);
    v[j * 4 + 3] = f2bf(f.w * inv);
  }
  u32 pk[8];
#pragma unroll
  for (int j = 0; j < 8; ++j) pk[j] = (u32)v[2 * j] | ((u32)v[2 * j + 1] << 16);
  u16* dst = Ebf + ((size_t)(b * T_N) + t0 + rr) * D_N + d0 + cg * 16;
  ((uint4*)dst)[0] = make_uint4(pk[0], pk[1], pk[2], pk[3]);
  ((uint4*)dst)[1] = make_uint4(pk[4], pk[5], pk[6], pk[7]);
#pragma unroll
  for (int j = 0; j < 16; ++j) tile[rr][cg * 16 + j] = v[j];
  __syncthreads();
  u16 w[16];
#pragma unroll
  for (int j = 0; j < 16; ++j) w[j] = tile[cg * 16 + j][rr];
#pragma unroll
  for (int j = 0; j < 8; ++j) pk[j] = (u32)w[2 * j] | ((u32)w[2 * j + 1] << 16);
  u16* dt = Etb + ((size_t)(b * D_N) + d0 + rr) * T_N + t0 + cg * 16;
  ((uint4*)dt)[0] = make_uint4(pk[0], pk[1], pk[2], pk[3]);
  ((uint4*)dt)[1] = make_uint4(pk[4], pk[5], pk[6], pk[7]);
}

// ---------------- k2: fused flash attention + cosine row loss ----------------
// 2-phase pipelined LDS staging: stage(next tile) -> compute(cur) -> barrier.
// E tile [32 tok][512 d] with chunk-XOR swizzle (chunk ^= tok&7, applied on the
// per-lane GLOBAL source so LDS dest stays linear); Et tile [512 d][32 tok]
// with 16B-slot rotation q = (s + r + (r>>2)) & 3 -> 2-way (free) ds_read_b128.
__launch_bounds__(256, 1)
__global__ void kflash(const float* __restrict__ pred, const float* __restrict__ invP,
                       const u16* __restrict__ Ebf, const u16* __restrict__ Etb,
                       const int* __restrict__ mask, float* __restrict__ rowloss,
                       float* __restrict__ flags) {
  int b = blockIdx.x & 7, rb = blockIdx.x >> 3;   // batch -> XCD pin (bid%8)
  int wid = threadIdx.x >> 6, lane = threadIdx.x & 63;
  int g = lane >> 4, c = lane & 15;
  int row0 = rb * 64 + wid * 16;

  __shared__ u64 mbits[32];
  __shared__ __align__(16) u16 pbuf[4][16][40];   // per-wave P relayout bounce
  __shared__ __align__(16) u16 els[2][32 * 512];  // 2 x 32KB E tiles
  __shared__ __align__(16) u16 etls[2][512 * 32]; // 2 x 32KB Et tiles

  const u16* Eb = Ebf + (size_t)b * T_N * D_N;
  const u16* Et = Etb + (size_t)b * D_N * T_N;

  // staging lane constants
  const int rr4 = lane >> 2, q4 = lane & 3;
  const int ssl = (q4 - rr4 - (rr4 >> 2)) & 3;    // Et: global slot for LDS slot q4
  const int q2 = (g + c + (c >> 2)) & 3;          // Et: LDS slot holding token-slot g

  auto stage = [&](int buf, int t) {
    int c0 = t * 32;
#pragma unroll
    for (int j = 0; j < 8; ++j) {                 // E: one 1KB token-row per instr
      int tok = j * 4 + wid;
      const u16* gs = Eb + (size_t)(c0 + tok) * D_N + ((lane ^ (tok & 7)) << 3);
      gload_lds16(gs, &els[buf][tok * 512]);
    }
#pragma unroll
    for (int j = 0; j < 8; ++j) {                 // Et: 16 64B d-rows per instr
      int kg = j * 4 + wid;
      const u16* gs = Et + (size_t)(kg * 16 + rr4) * T_N + c0 + (ssl << 3);
      gload_lds16(gs, &etls[buf][kg * 512]);
    }
  };

  for (int chunk = wid; chunk < 32; chunk += 4) {
    int col = chunk * 64 + lane;
    u64 bal = __ballot(mask[b * T_N + col] == 0); // True mask = PAD
    if (lane == 0) mbits[chunk] = bal;
  }

  stage(0, 0);

  // P fragments: fp32 normalize on the fly; loads overlap tile-0 staging.
  bf16x8 pf[16];
  {
    int prow = row0 + c;
    const float* pr = pred + ((size_t)(b * T_N) + prow) * D_N;
    float inv = invP[b * T_N + prow];
#pragma unroll
    for (int kk = 0; kk < 16; ++kk) {
      float4 v0 = *(const float4*)(pr + kk * 32 + g * 8);
      float4 v1 = *(const float4*)(pr + kk * 32 + g * 8 + 4);
      bf16x8 f;
      f[0] = (__bf16)(v0.x * inv); f[1] = (__bf16)(v0.y * inv);
      f[2] = (__bf16)(v0.z * inv); f[3] = (__bf16)(v0.w * inv);
      f[4] = (__bf16)(v1.x * inv); f[5] = (__bf16)(v1.y * inv);
      f[6] = (__bf16)(v1.z * inv); f[7] = (__bf16)(v1.w * inv);
      pf[kk] = f;
    }
  }

  __syncthreads();   // tile 0 staged; mbits visible

  u64 anyv = 0;
#pragma unroll
  for (int i = 0; i < 32; ++i) anyv |= mbits[i];
  if (rb == 0 && threadIdx.x == 0) flags[b] = (anyv != 0ULL) ? 1.f : 0.f;
  if (anyv == 0ULL) {
    if (threadIdx.x < 64) rowloss[b * T_N + rb * 64 + threadIdx.x] = 0.f;
    return;
  }

  f32x4 zero = {0.f, 0.f, 0.f, 0.f};
  f32x4 eh[32];
#pragma unroll
  for (int n = 0; n < 32; ++n) eh[n] = zero;
  float lsum[4] = {0.f, 0.f, 0.f, 0.f};
  float mrun[4] = {-3e38f, -3e38f, -3e38f, -3e38f};

#pragma unroll 1
  for (int t = 0; t < T_N / 32; ++t) {
    int cur = t & 1;
    if (t + 1 < T_N / 32) stage(cur ^ 1, t + 1);   // issue-early: hides under compute
    int c0 = t * 32;

    f32x4 s0 = zero, s1 = zero;
    const u16* el = &els[cur][0];
#pragma unroll
    for (int kk = 0; kk < 16; ++kk) {
      int cs = kk * 4 + g;
      bf16x8 b0 = *(const bf16x8*)&el[(size_t)c * 512 + ((cs ^ (c & 7)) << 3)];
      bf16x8 b1 = *(const bf16x8*)&el[(size_t)(16 + c) * 512 + ((cs ^ (c & 7)) << 3)];
      s0 = __builtin_amdgcn_mfma_f32_16x16x32_bf16(pf[kk], b0, s0, 0, 0, 0);
      s1 = __builtin_amdgcn_mfma_f32_16x16x32_bf16(pf[kk], b1, s1, 0, 0, 0);
    }

    int col0 = c0 + c;
    bool v0 = (mbits[col0 >> 6] >> (col0 & 63)) & 1ULL;
    bool v1 = (mbits[(col0 + 16) >> 6] >> ((col0 + 16) & 63)) & 1ULL;
    float x0[4], x1[4], tm[4];
    bool need = false;
#pragma unroll
    for (int r = 0; r < 4; ++r) {
      x0[r] = v0 ? TAU * s0[r] : -1e30f;
      x1[r] = v1 ? TAU * s1[r] : -1e30f;
      float t2 = fmaxf(x0[r], x1[r]);
      t2 = fmaxf(t2, __shfl_xor(t2, 1));
      t2 = fmaxf(t2, __shfl_xor(t2, 2));
      t2 = fmaxf(t2, __shfl_xor(t2, 4));
      t2 = fmaxf(t2, __shfl_xor(t2, 8));
      tm[r] = t2;
      need = need || (t2 > mrun[r] + 8.f);
    }
    if (__any(need)) {  // defer-max (T13)
      float sc[4];
#pragma unroll
      for (int r = 0; r < 4; ++r) {
        float nm = fmaxf(mrun[r], tm[r]);
        sc[r] = __expf(mrun[r] - nm);
        mrun[r] = nm;
        lsum[r] *= sc[r];
      }
#pragma unroll
      for (int n = 0; n < 32; ++n) {
        eh[n][0] *= sc[0]; eh[n][1] *= sc[1];
        eh[n][2] *= sc[2]; eh[n][3] *= sc[3];
      }
    }
#pragma unroll
    for (int r = 0; r < 4; ++r) {
      float p0 = v0 ? __expf(x0[r] - mrun[r]) : 0.f;
      float p1 = v1 ? __expf(x1[r] - mrun[r]) : 0.f;
      lsum[r] += p0 + p1;
      pbuf[wid][g * 4 + r][c] = f2bf(p0);        // C-layout -> A-layout bounce
      pbuf[wid][g * 4 + r][16 + c] = f2bf(p1);
    }
    bf16x8 af = *(const bf16x8*)&pbuf[wid][c][g * 8];
    const u16* et = &etls[cur][0];
#pragma unroll
    for (int n = 0; n < 32; ++n) {
      int r = n * 16 + c;
      bf16x8 bv = *(const bf16x8*)&et[r * 32 + q2 * 8];
      eh[n] = __builtin_amdgcn_mfma_f32_16x16x32_bf16(af, bv, eh[n], 0, 0, 0);
    }
    __syncthreads();   // drains staging vmcnt + frees els/etls[cur]
  }

  // epilogue: cos per row
#pragma unroll
  for (int r = 0; r < 4; ++r) {
    float t = lsum[r];
    t += __shfl_xor(t, 1); t += __shfl_xor(t, 2);
    t += __shfl_xor(t, 4); t += __shfl_xor(t, 8);
    lsum[r] = t;
  }
  float out_dot[4], out_en2[4];
#pragma unroll
  for (int r = 0; r < 4; ++r) {
    int prow = row0 + g * 4 + r;
    const float* pr = pred + ((size_t)(b * T_N) + prow) * D_N;
    float inv = invP[b * T_N + prow];
    float d = 0.f, e2 = 0.f;
#pragma unroll
    for (int n = 0; n < 32; ++n) {
      float ev = eh[n][r];
      d += ev * (pr[n * 16 + c] * inv);
      e2 += ev * ev;
    }
    d += __shfl_xor(d, 1); d += __shfl_xor(d, 2);
    d += __shfl_xor(d, 4); d += __shfl_xor(d, 8);
    e2 += __shfl_xor(e2, 1); e2 += __shfl_xor(e2, 2);
    e2 += __shfl_xor(e2, 4); e2 += __shfl_xor(e2, 8);
    out_dot[r] = d; out_en2[r] = e2;
  }
  if (c == 0) {
#pragma unroll
    for (int r = 0; r < 4; ++r) {
      int prow = row0 + g * 4 + r;
      float denom = fmaxf(sqrtf(out_en2[r]), 1e-8f * lsum[r]);
      float cosv = out_dot[r] / denom;
      rowloss[b * T_N + prow] = 1.f - cosv;
    }
  }
}

// ---------------- k3: deterministic final reduction ----------------
__global__ void kreduce(const float* __restrict__ rowloss, const float* __restrict__ flags,
                        float* __restrict__ out) {
  __shared__ float sm[256];
  float s = 0.f;
  for (int i = threadIdx.x; i < B_N * T_N; i += 256) s += rowloss[i];
  sm[threadIdx.x] = s;
  __syncthreads();
#pragma unroll
  for (int st = 128; st >= 1; st >>= 1) {
    if ((int)threadIdx.x < st) sm[threadIdx.x] += sm[threadIdx.x + st];
    __syncthreads();
  }
  if (threadIdx.x == 0) {
    float cnt = 0.f;
    for (int i = 0; i < B_N; ++i) cnt += flags[i];
    cnt *= (float)T_N;
    float loss = (cnt > 0.f) ? sm[0] / fmaxf(cnt, 1.f) : 0.f;
    out[0] = loss;
    out[1] = (cnt > 0.f) ? 1.f - loss : 0.f;
  }
}

extern "C" void kernel_launch(void* const* d_in, const int* in_sizes, int n_in,
                              void* d_out, int out_size, void* d_ws, size_t ws_size,
                              hipStream_t stream) {
  const float* pred = (const float*)d_in[0];
  const float* text = (const float*)d_in[1];
  const int* mask = (const int*)d_in[2];
  char* ws = (char*)d_ws;
  const size_t EB = (size_t)B_N * T_N * D_N * 2;  // bytes of one bf16 tensor
  u16* Ebf = (u16*)ws;
  u16* Etb = (u16*)(ws + EB);
  float* invP = (float*)(ws + 2 * EB);
  float* invE = (float*)(ws + 2 * EB + 65536);
  float* rowloss = (float*)(ws + 2 * EB + 131072);
  float* flags = (float*)(ws + 2 * EB + 196608);
  float* out = (float*)d_out;

  knorm<<<dim3(2 * B_N * T_N / 4), dim3(256), 0, stream>>>(pred, text, invP, invE);
  kprep<<<dim3(D_N / 64, T_N / 64, B_N), dim3(256), 0, stream>>>(text, invE, Ebf, Etb);
  kflash<<<dim3(B_N * T_N / 64), dim3(256), 0, stream>>>(pred, invP, Ebf, Etb, mask, rowloss, flags);
  kreduce<<<dim3(1), dim3(256), 0, stream>>>(rowloss, flags, out);
}

// Round 3
// 207.910 us; speedup vs baseline: 2.6354x; 1.1598x over previous
//
#include <hip/hip_runtime.h>
#include <cstdint>

typedef float f32x4 __attribute__((ext_vector_type(4)));
typedef unsigned char u8;
typedef unsigned short u16;
typedef unsigned int u32;
typedef unsigned long long u64;

#define B_N 8
#define T_N 2048
#define D_N 512
#define TAU 5.0f
#define THR 5.0f   // defer-max threshold; e^5=148 < e4m3 max 448

__device__ __forceinline__ void gload_lds16(const u8* g, u8* l) {
  __builtin_amdgcn_global_load_lds(
      (const __attribute__((address_space(1))) u32*)g,
      (__attribute__((address_space(3))) u32*)l, 16, 0, 0);
}

// pack 4 floats -> 4 fp8(e4m3) bytes in a u32
__device__ __forceinline__ u32 pk4_fp8(float a, float b, float c, float d) {
  int w = __builtin_amdgcn_cvt_pk_fp8_f32(a, b, 0, 0);
  w = __builtin_amdgcn_cvt_pk_fp8_f32(c, d, w, 1);
  return (u32)w;
}

// ---------------- k0: per-row inverse L2 norms for pred and text ----------------
__global__ void knorm(const float* __restrict__ pred, const float* __restrict__ text,
                      float* __restrict__ invP, float* __restrict__ invE) {
  int wid = threadIdx.x >> 6, lane = threadIdx.x & 63;
  int row = blockIdx.x * 4 + wid;              // 0..2*B*T-1
  const float* src = (row < B_N * T_N) ? pred : text;
  int r = row & (B_N * T_N - 1);
  const float4* p = (const float4*)(src + (size_t)r * D_N);
  float4 a = p[lane * 2];
  float4 bb = p[lane * 2 + 1];
  float s = a.x * a.x + a.y * a.y + a.z * a.z + a.w * a.w
          + bb.x * bb.x + bb.y * bb.y + bb.z * bb.z + bb.w * bb.w;
#pragma unroll
  for (int m = 32; m >= 1; m >>= 1) s += __shfl_xor(s, m);
  if (lane == 0) {
    float inv = 1.0f / fmaxf(sqrtf(s), 1e-12f);
    (row < B_N * T_N ? invP : invE)[r] = inv;
  }
}

// ---------------- k1: normalized E as fp8: row-major Ebf[T][D] and tile-blocked
// Etb[t/32][D][32tok] (per batch) ----------------
__global__ void kprep(const float* __restrict__ text, const float* __restrict__ invE,
                      u8* __restrict__ Ebf, u8* __restrict__ Etb) {
  __shared__ u8 tile[64][68];
  int b = blockIdx.z, t0 = blockIdx.y * 64, d0 = blockIdx.x * 64;
  int rr = threadIdx.x >> 2, cg = threadIdx.x & 3;
  const float* src = text + ((size_t)(b * T_N) + t0 + rr) * D_N + d0 + cg * 16;
  float inv = invE[b * T_N + t0 + rr];
  u32 w[4];
#pragma unroll
  for (int j = 0; j < 4; ++j) {
    float4 f0 = *(const float4*)(src + j * 4);
    w[j] = pk4_fp8(f0.x * inv, f0.y * inv, f0.z * inv, f0.w * inv);
  }
  u8* dst = Ebf + ((size_t)(b * T_N) + t0 + rr) * D_N + d0 + cg * 16;
  *(uint4*)dst = make_uint4(w[0], w[1], w[2], w[3]);
#pragma unroll
  for (int j = 0; j < 16; ++j) tile[rr][cg * 16 + j] = (u8)((w[j >> 2] >> ((j & 3) * 8)) & 0xff);
  __syncthreads();
  u32 v[4];
#pragma unroll
  for (int j = 0; j < 4; ++j) {
    u32 x = 0;
#pragma unroll
    for (int k = 0; k < 4; ++k) x |= (u32)tile[cg * 16 + j * 4 + k][rr] << (k * 8);
    v[j] = x;
  }
  // toks t0+cg*16..+15 at fixed d=d0+rr -> block tb, local toks (cg&1)*16..
  int tb = (t0 >> 5) + (cg >> 1);
  u8* dt = Etb + (((size_t)(b * 64 + tb) * D_N) + d0 + rr) * 32 + (cg & 1) * 16;
  *(uint4*)dt = make_uint4(v[0], v[1], v[2], v[3]);
}

// ---------------- k2: fused flash attention + cosine row loss (fp8 operands) ----------------
__launch_bounds__(256, 2)
__global__ void kflash(const float* __restrict__ pred, const float* __restrict__ invP,
                       const u8* __restrict__ Ebf, const u8* __restrict__ Etb,
                       const int* __restrict__ mask, float* __restrict__ rowloss,
                       float* __restrict__ flags) {
  int b = blockIdx.x & 7, rb = blockIdx.x >> 3;   // batch -> XCD pin
  int wid = threadIdx.x >> 6, lane = threadIdx.x & 63;
  int g = lane >> 4, c = lane & 15;
  int row0 = rb * 64 + wid * 16;

  __shared__ u64 mbits[32];
  __shared__ __align__(16) u8 pbuf[4][16][40];    // per-wave P-weights (fp8) + pad
  __shared__ __align__(16) u8 els[2][32 * 512];   // 2 x 16KB E tiles [tok][d] (swizzled)
  __shared__ __align__(16) u8 etls[2][512 * 32];  // 2 x 16KB Et tiles [d][tok]

  const u8* Eb = Ebf + (size_t)b * T_N * D_N;
  const u8* Etbase = Etb + ((size_t)b * 64) * (D_N * 32);

  auto stage = [&](int buf, int t) {
#pragma unroll
    for (int j = 0; j < 4; ++j) {                 // E: 1KB (2 rows) per instr
      int tok2 = j * 8 + wid * 2;
      int tok = tok2 + (lane >> 5);
      int q = lane & 31;
      int swz = ((tok & 3) << 4) | (((tok >> 2) & 1) << 6);
      const u8* gs = Eb + (size_t)(t * 32 + tok) * D_N + ((q << 4) ^ swz);
      gload_lds16(gs, &els[buf][tok2 * 512]);
    }
#pragma unroll
    for (int j = 0; j < 4; ++j) {                 // Et: linear 1KB per instr
      int i = j * 4 + wid;
      const u8* gs = Etbase + ((size_t)t << 14) + (i << 10) + ((lane & 63) << 4);
      gload_lds16(gs, &etls[buf][i << 10]);
    }
  };

  for (int chunk = wid; chunk < 32; chunk += 4) {
    int col = chunk * 64 + lane;
    u64 bal = __ballot(mask[b * T_N + col] == 0); // True mask = PAD
    if (lane == 0) mbits[chunk] = bal;
  }

  stage(0, 0);

  // P fragments: fp32 normalize -> fp8 pack; overlaps tile-0 staging.
  long pf[16];
  {
    int prow = row0 + c;
    const float* pr = pred + ((size_t)(b * T_N) + prow) * D_N;
    float inv = invP[b * T_N + prow];
#pragma unroll
    for (int kk = 0; kk < 16; ++kk) {
      float4 v0 = *(const float4*)(pr + kk * 32 + g * 8);
      float4 v1 = *(const float4*)(pr + kk * 32 + g * 8 + 4);
      u32 lo = pk4_fp8(v0.x * inv, v0.y * inv, v0.z * inv, v0.w * inv);
      u32 hi = pk4_fp8(v1.x * inv, v1.y * inv, v1.z * inv, v1.w * inv);
      pf[kk] = (long)(((u64)hi << 32) | lo);
    }
  }

  __syncthreads();   // tile 0 staged; mbits visible

  u64 anyv = 0;
#pragma unroll
  for (int i = 0; i < 32; ++i) anyv |= mbits[i];
  if (rb == 0 && threadIdx.x == 0) flags[b] = (anyv != 0ULL) ? 1.f : 0.f;
  if (anyv == 0ULL) {
    if (threadIdx.x < 64) rowloss[b * T_N + rb * 64 + threadIdx.x] = 0.f;
    return;
  }

  f32x4 zero = {0.f, 0.f, 0.f, 0.f};
  f32x4 eh[32];
#pragma unroll
  for (int n = 0; n < 32; ++n) eh[n] = zero;
  float lsum[4] = {0.f, 0.f, 0.f, 0.f};
  float mrun[4] = {-3e38f, -3e38f, -3e38f, -3e38f};

  const int swzE = ((c & 3) << 4) | (((c >> 2) & 1) << 6);

#pragma unroll 1
  for (int t = 0; t < T_N / 32; ++t) {
    int cur = t & 1;
    if (t + 1 < T_N / 32) stage(cur ^ 1, t + 1);   // issue-early
    int c0 = t * 32;

    // S = P . E^T : 4 independent MFMA chains of 8
    f32x4 sa0 = zero, sb0 = zero, sa1 = zero, sb1 = zero;
    const u8* el = &els[cur][0];
#pragma unroll
    for (int kk = 0; kk < 16; ++kk) {
      int o = (kk * 32 + (g << 3)) ^ swzE;
      long b0 = *(const long*)(el + (size_t)c * 512 + o);
      long b1 = *(const long*)(el + (size_t)(16 + c) * 512 + o);
      if (kk & 1) {
        sb0 = __builtin_amdgcn_mfma_f32_16x16x32_fp8_fp8(pf[kk], b0, sb0, 0, 0, 0);
        sb1 = __builtin_amdgcn_mfma_f32_16x16x32_fp8_fp8(pf[kk], b1, sb1, 0, 0, 0);
      } else {
        sa0 = __builtin_amdgcn_mfma_f32_16x16x32_fp8_fp8(pf[kk], b0, sa0, 0, 0, 0);
        sa1 = __builtin_amdgcn_mfma_f32_16x16x32_fp8_fp8(pf[kk], b1, sa1, 0, 0, 0);
      }
    }
    f32x4 s0 = sa0 + sb0, s1 = sa1 + sb1;

    int col0 = c0 + c;
    bool v0 = (mbits[col0 >> 6] >> (col0 & 63)) & 1ULL;
    bool v1 = (mbits[(col0 + 16) >> 6] >> ((col0 + 16) & 63)) & 1ULL;
    float x0[4], x1[4], tm[4];
    bool need = false;
#pragma unroll
    for (int r = 0; r < 4; ++r) {
      x0[r] = v0 ? TAU * s0[r] : -1e30f;
      x1[r] = v1 ? TAU * s1[r] : -1e30f;
      float t2 = fmaxf(x0[r], x1[r]);
      t2 = fmaxf(t2, __shfl_xor(t2, 1));
      t2 = fmaxf(t2, __shfl_xor(t2, 2));
      t2 = fmaxf(t2, __shfl_xor(t2, 4));
      t2 = fmaxf(t2, __shfl_xor(t2, 8));
      tm[r] = t2;
      need = need || (t2 > mrun[r] + THR);
    }
    if (__any(need)) {  // defer-max (T13), THR=5 for fp8 range
      float sc[4];
#pragma unroll
      for (int r = 0; r < 4; ++r) {
        float nm = fmaxf(mrun[r], tm[r]);
        sc[r] = __expf(mrun[r] - nm);
        mrun[r] = nm;
        lsum[r] *= sc[r];
      }
#pragma unroll
      for (int n = 0; n < 32; ++n) {
        eh[n][0] *= sc[0]; eh[n][1] *= sc[1];
        eh[n][2] *= sc[2]; eh[n][3] *= sc[3];
      }
    }
#pragma unroll
    for (int r = 0; r < 4; ++r) {
      float p0 = v0 ? __expf(x0[r] - mrun[r]) : 0.f;
      float p1 = v1 ? __expf(x1[r] - mrun[r]) : 0.f;
      lsum[r] += p0 + p1;
      u32 pk2 = (u32)__builtin_amdgcn_cvt_pk_fp8_f32(p0, p1, 0, 0);
      pbuf[wid][g * 4 + r][c] = (u8)(pk2 & 0xff);        // tok c
      pbuf[wid][g * 4 + r][16 + c] = (u8)((pk2 >> 8) & 0xff); // tok 16+c
    }
    long af = *(const long*)(&pbuf[wid][c][g * 8]);
    const u8* et = &etls[cur][0];
#pragma unroll
    for (int n = 0; n < 32; ++n) {
      long bv = *(const long*)(et + ((n * 16 + c) << 5) + (g << 3));
      eh[n] = __builtin_amdgcn_mfma_f32_16x16x32_fp8_fp8(af, bv, eh[n], 0, 0, 0);
    }
    __syncthreads();   // drains staging vmcnt + frees tiles[cur]
  }

  // epilogue: cos per row
#pragma unroll
  for (int r = 0; r < 4; ++r) {
    float t = lsum[r];
    t += __shfl_xor(t, 1); t += __shfl_xor(t, 2);
    t += __shfl_xor(t, 4); t += __shfl_xor(t, 8);
    lsum[r] = t;
  }
  float out_dot[4], out_en2[4];
#pragma unroll
  for (int r = 0; r < 4; ++r) {
    int prow = row0 + g * 4 + r;
    const float* pr = pred + ((size_t)(b * T_N) + prow) * D_N;
    float inv = invP[b * T_N + prow];
    float d = 0.f, e2 = 0.f;
#pragma unroll
    for (int n = 0; n < 32; ++n) {
      float ev = eh[n][r];
      d += ev * (pr[n * 16 + c] * inv);
      e2 += ev * ev;
    }
    d += __shfl_xor(d, 1); d += __shfl_xor(d, 2);
    d += __shfl_xor(d, 4); d += __shfl_xor(d, 8);
    e2 += __shfl_xor(e2, 1); e2 += __shfl_xor(e2, 2);
    e2 += __shfl_xor(e2, 4); e2 += __shfl_xor(e2, 8);
    out_dot[r] = d; out_en2[r] = e2;
  }
  if (c == 0) {
#pragma unroll
    for (int r = 0; r < 4; ++r) {
      int prow = row0 + g * 4 + r;
      float denom = fmaxf(sqrtf(out_en2[r]), 1e-8f * lsum[r]);
      float cosv = out_dot[r] / denom;
      rowloss[b * T_N + prow] = 1.f - cosv;
    }
  }
}

// ---------------- k3: deterministic final reduction ----------------
__global__ void kreduce(const float* __restrict__ rowloss, const float* __restrict__ flags,
                        float* __restrict__ out) {
  __shared__ float sm[256];
  float s = 0.f;
  for (int i = threadIdx.x; i < B_N * T_N; i += 256) s += rowloss[i];
  sm[threadIdx.x] = s;
  __syncthreads();
#pragma unroll
  for (int st = 128; st >= 1; st >>= 1) {
    if ((int)threadIdx.x < st) sm[threadIdx.x] += sm[threadIdx.x + st];
    __syncthreads();
  }
  if (threadIdx.x == 0) {
    float cnt = 0.f;
    for (int i = 0; i < B_N; ++i) cnt += flags[i];
    cnt *= (float)T_N;
    float loss = (cnt > 0.f) ? sm[0] / fmaxf(cnt, 1.f) : 0.f;
    out[0] = loss;
    out[1] = (cnt > 0.f) ? 1.f - loss : 0.f;
  }
}

extern "C" void kernel_launch(void* const* d_in, const int* in_sizes, int n_in,
                              void* d_out, int out_size, void* d_ws, size_t ws_size,
                              hipStream_t stream) {
  const float* pred = (const float*)d_in[0];
  const float* text = (const float*)d_in[1];
  const int* mask = (const int*)d_in[2];
  char* ws = (char*)d_ws;
  const size_t EB8 = (size_t)B_N * T_N * D_N;     // bytes of one fp8 tensor (8MB)
  u8* Ebf = (u8*)ws;
  u8* Etb = (u8*)(ws + EB8);
  float* invP = (float*)(ws + 2 * EB8);
  float* invE = (float*)(ws + 2 * EB8 + 65536);
  float* rowloss = (float*)(ws + 2 * EB8 + 131072);
  float* flags = (float*)(ws + 2 * EB8 + 196608);
  float* out = (float*)d_out;

  knorm<<<dim3(2 * B_N * T_N / 4), dim3(256), 0, stream>>>(pred, text, invP, invE);
  kprep<<<dim3(D_N / 64, T_N / 64, B_N), dim3(256), 0, stream>>>(text, invE, Ebf, Etb);
  kflash<<<dim3(B_N * T_N / 64), dim3(256), 0, stream>>>(pred, invP, Ebf, Etb, mask, rowloss, flags);
  kreduce<<<dim3(1), dim3(256), 0, stream>>>(rowloss, flags, out);
}

// Round 4
// 142.851 us; speedup vs baseline: 3.8357x; 1.4554x over previous
//
#include <hip/hip_runtime.h>
#include <cstdint>

typedef float f32x4 __attribute__((ext_vector_type(4)));
typedef unsigned char u8;
typedef unsigned short u16;
typedef unsigned int u32;
typedef unsigned long long u64;

#define B_N 8
#define T_N 2048
#define D_N 512
#define TAU 5.0f
#define THR 5.0f            // defer-max threshold; e^5=148 < e4m3 max 448
#define NROW (B_N * T_N)    // 16384

__device__ __forceinline__ void gload_lds16(const u8* g, u8* l) {
  __builtin_amdgcn_global_load_lds(
      (const __attribute__((address_space(1))) u32*)g,
      (__attribute__((address_space(3))) u32*)l, 16, 0, 0);
}

// pack 4 floats -> 4 fp8(e4m3) bytes in a u32
__device__ __forceinline__ u32 pk4_fp8(float a, float b, float c, float d) {
  int w = __builtin_amdgcn_cvt_pk_fp8_f32(a, b, 0, 0);
  w = __builtin_amdgcn_cvt_pk_fp8_f32(c, d, w, 1);
  return (u32)w;
}

__device__ __forceinline__ u16 f2bf16(float x) {   // RNE f32->bf16
  u32 u = __builtin_bit_cast(u32, x);
  u32 r = u + 0x7fffu + ((u >> 16) & 1u);
  return (u16)(r >> 16);
}
__device__ __forceinline__ float bf2f(u16 v) {
  u32 u = ((u32)v) << 16;
  return __builtin_bit_cast(float, u);
}

// ---------------- k1: normalize E rows (fused norm) and emit fp8 in MFMA
// fragment order.  EF[b][t][kk][g][tok]*8B  (S-phase B-operand),
// ET[b][t][n][g][c]*8B (PV-phase B-operand). Both 16KB per 32-token tile. ----
__global__ void kprep(const float* __restrict__ text,
                      u8* __restrict__ EF, u8* __restrict__ ET) {
  __shared__ u8 tile[32][528];   // 528 = 16B-aligned rows, bank-rotating (+4/row)
  int b = blockIdx.y, t = blockIdx.x;
  int tr = threadIdx.x;
  int row = tr >> 3, seg = tr & 7;          // 32 rows x 8 segs of 64 d
  const float* src = text + ((size_t)b * T_N + t * 32 + row) * D_N + seg * 64;
  float4 v[16];
  float ss = 0.f;
#pragma unroll
  for (int j = 0; j < 16; ++j) {
    v[j] = *(const float4*)(src + j * 4);
    ss += v[j].x*v[j].x + v[j].y*v[j].y + v[j].z*v[j].z + v[j].w*v[j].w;
  }
  ss += __shfl_xor(ss, 1); ss += __shfl_xor(ss, 2); ss += __shfl_xor(ss, 4);
  float inv = 1.f / fmaxf(sqrtf(ss), 1e-12f);
  u32 w[16];
#pragma unroll
  for (int j = 0; j < 16; ++j)
    w[j] = pk4_fp8(v[j].x*inv, v[j].y*inv, v[j].z*inv, v[j].w*inv);
  uint4* ldst = (uint4*)&tile[row][seg * 64];
#pragma unroll
  for (int j = 0; j < 4; ++j)
    ldst[j] = make_uint4(w[4*j], w[4*j+1], w[4*j+2], w[4*j+3]);
  __syncthreads();
  size_t tbase = ((size_t)(b * 64 + t)) << 14;
  {
    // Efrag: f = tr*8+i ; kk=f>>7, g=(f>>5)&3, tok=f&31 ; content E[tok][kk*32+g*8..+8]
    u32 acc[16];
#pragma unroll
    for (int i = 0; i < 8; ++i) {
      int f = tr * 8 + i;
      uint2 vv = *(const uint2*)&tile[f & 31][((f >> 7) << 5) + (((f >> 5) & 3) << 3)];
      acc[2*i] = vv.x; acc[2*i+1] = vv.y;
    }
    uint4* dst = (uint4*)(EF + tbase + tr * 64);
#pragma unroll
    for (int j = 0; j < 4; ++j)
      dst[j] = make_uint4(acc[4*j], acc[4*j+1], acc[4*j+2], acc[4*j+3]);
  }
  {
    // Etfrag: f = tr*8+i ; n=f>>6, g=(f>>4)&3, c=f&15 ; content E[g*8+j][n*16+c]
    u32 acc[16];
#pragma unroll
    for (int i = 0; i < 8; ++i) {
      int f = tr * 8 + i;
      int n = f >> 6, g2 = (f >> 4) & 3, cc = f & 15;
      u32 lo = 0, hi = 0;
#pragma unroll
      for (int j = 0; j < 4; ++j) lo |= (u32)tile[g2*8 + j][n*16 + cc] << (8*j);
#pragma unroll
      for (int j = 0; j < 4; ++j) hi |= (u32)tile[g2*8 + 4 + j][n*16 + cc] << (8*j);
      acc[2*i] = lo; acc[2*i+1] = hi;
    }
    uint4* dst = (uint4*)(ET + tbase + tr * 64);
#pragma unroll
    for (int j = 0; j < 4; ++j)
      dst[j] = make_uint4(acc[4*j], acc[4*j+1], acc[4*j+2], acc[4*j+3]);
  }
}

// ---------------- k2: flash attention over a column HALF; partial (m,l,O) out.
// Grid 512 = 2 blocks/CU. Linear staging, fragment-order LDS (conflict-free). --
__launch_bounds__(256, 2)
__global__ void kflash(const float* __restrict__ pred,
                       const u8* __restrict__ EF, const u8* __restrict__ ET,
                       const int* __restrict__ mask,
                       u16* __restrict__ Opart, float* __restrict__ Mpart,
                       float* __restrict__ Lpart) {
  int b = blockIdx.x & 7;                 // batch -> XCD pin
  int rem = blockIdx.x >> 3;
  int rb = rem & 31, h = rem >> 5;        // row-block, column half
  int wid = threadIdx.x >> 6, lane = threadIdx.x & 63;
  int g = lane >> 4, c = lane & 15;
  int row0 = rb * 64 + wid * 16;
  int t0 = h * 32;

  __shared__ u64 mbits[32];
  __shared__ __align__(16) u8 pbuf[4][16][40];
  __shared__ __align__(16) u8 els[2][16384];
  __shared__ __align__(16) u8 etls[2][16384];

  const u8* EFb = EF + (((size_t)(b * 64)) << 14) + (lane << 4);
  const u8* ETb = ET + (((size_t)(b * 64)) << 14) + (lane << 4);

  auto stage = [&](int buf, int t) {
    size_t tb = ((size_t)t) << 14;
#pragma unroll
    for (int j = 0; j < 4; ++j) {
      int ch = j * 4 + wid;
      gload_lds16(EFb + tb + (ch << 10), &els[buf][ch << 10]);
    }
#pragma unroll
    for (int j = 0; j < 4; ++j) {
      int ch = j * 4 + wid;
      gload_lds16(ETb + tb + (ch << 10), &etls[buf][ch << 10]);
    }
  };

  for (int chunk = wid; chunk < 32; chunk += 4) {
    int col = chunk * 64 + lane;
    u64 bal = __ballot(mask[b * T_N + col] == 0);  // True mask = PAD
    if (lane == 0) mbits[chunk] = bal;
  }

  stage(0, t0);

  // P fragments: two-pass (norm-sum, then fp8 pack); overlaps tile-0 staging.
  long pf[16];
  {
    int prow = row0 + c;
    const float* pr = pred + ((size_t)(b * T_N) + prow) * D_N;
    float ss = 0.f;
#pragma unroll
    for (int kk = 0; kk < 16; ++kk) {
      float4 v0 = *(const float4*)(pr + kk * 32 + g * 8);
      float4 v1 = *(const float4*)(pr + kk * 32 + g * 8 + 4);
      ss += v0.x*v0.x + v0.y*v0.y + v0.z*v0.z + v0.w*v0.w
          + v1.x*v1.x + v1.y*v1.y + v1.z*v1.z + v1.w*v1.w;
    }
    ss += __shfl_xor(ss, 16);
    ss += __shfl_xor(ss, 32);
    float inv = 1.f / fmaxf(sqrtf(ss), 1e-12f);
#pragma unroll
    for (int kk = 0; kk < 16; ++kk) {
      float4 v0 = *(const float4*)(pr + kk * 32 + g * 8);
      float4 v1 = *(const float4*)(pr + kk * 32 + g * 8 + 4);
      u32 lo = pk4_fp8(v0.x*inv, v0.y*inv, v0.z*inv, v0.w*inv);
      u32 hi = pk4_fp8(v1.x*inv, v1.y*inv, v1.z*inv, v1.w*inv);
      pf[kk] = (long)(((u64)hi << 32) | lo);
    }
  }

  __syncthreads();   // tile t0 staged; mbits visible

  f32x4 zero = {0.f, 0.f, 0.f, 0.f};
  f32x4 eh[32];
#pragma unroll
  for (int n = 0; n < 32; ++n) eh[n] = zero;
  float lsum[4] = {0.f, 0.f, 0.f, 0.f};
  float mrun[4] = {-3e38f, -3e38f, -3e38f, -3e38f};

  const int ebase = g * 256 + c * 8;     // S-read lane offset
  const int pvb = g * 128 + c * 8;       // PV-read lane offset

#pragma unroll 1
  for (int tt = 0; tt < 32; ++tt) {
    int t = t0 + tt;
    int cur = tt & 1;
    if (tt + 1 < 32) stage(cur ^ 1, t + 1);   // issue-early
    int c0 = t * 32;

    // S = P . E^T : 4 independent MFMA chains of 8
    f32x4 sa0 = zero, sb0 = zero, sa1 = zero, sb1 = zero;
    const u8* el = &els[cur][0];
#pragma unroll
    for (int kk = 0; kk < 16; ++kk) {
      long b0 = *(const long*)(el + kk * 1024 + ebase);
      long b1 = *(const long*)(el + kk * 1024 + ebase + 128);
      if (kk & 1) {
        sb0 = __builtin_amdgcn_mfma_f32_16x16x32_fp8_fp8(pf[kk], b0, sb0, 0, 0, 0);
        sb1 = __builtin_amdgcn_mfma_f32_16x16x32_fp8_fp8(pf[kk], b1, sb1, 0, 0, 0);
      } else {
        sa0 = __builtin_amdgcn_mfma_f32_16x16x32_fp8_fp8(pf[kk], b0, sa0, 0, 0, 0);
        sa1 = __builtin_amdgcn_mfma_f32_16x16x32_fp8_fp8(pf[kk], b1, sa1, 0, 0, 0);
      }
    }
    f32x4 s0 = sa0 + sb0, s1 = sa1 + sb1;

    int col0 = c0 + c;
    bool v0 = (mbits[col0 >> 6] >> (col0 & 63)) & 1ULL;
    bool v1 = (mbits[(col0 + 16) >> 6] >> ((col0 + 16) & 63)) & 1ULL;
    float x0[4], x1[4], tm[4];
    bool need = false;
#pragma unroll
    for (int r = 0; r < 4; ++r) {
      x0[r] = v0 ? TAU * s0[r] : -1e30f;
      x1[r] = v1 ? TAU * s1[r] : -1e30f;
      float t2 = fmaxf(x0[r], x1[r]);
      t2 = fmaxf(t2, __shfl_xor(t2, 1));
      t2 = fmaxf(t2, __shfl_xor(t2, 2));
      t2 = fmaxf(t2, __shfl_xor(t2, 4));
      t2 = fmaxf(t2, __shfl_xor(t2, 8));
      tm[r] = t2;
      need = need || (t2 > mrun[r] + THR);
    }
    if (__any(need)) {  // defer-max (T13)
      float sc[4];
#pragma unroll
      for (int r = 0; r < 4; ++r) {
        float nm = fmaxf(mrun[r], tm[r]);
        sc[r] = __expf(mrun[r] - nm);
        mrun[r] = nm;
        lsum[r] *= sc[r];
      }
#pragma unroll
      for (int n = 0; n < 32; ++n) {
        eh[n][0] *= sc[0]; eh[n][1] *= sc[1];
        eh[n][2] *= sc[2]; eh[n][3] *= sc[3];
      }
    }
#pragma unroll
    for (int r = 0; r < 4; ++r) {
      float p0 = v0 ? __expf(x0[r] - mrun[r]) : 0.f;
      float p1 = v1 ? __expf(x1[r] - mrun[r]) : 0.f;
      lsum[r] += p0 + p1;
      u32 pk2 = (u32)__builtin_amdgcn_cvt_pk_fp8_f32(p0, p1, 0, 0);
      pbuf[wid][g * 4 + r][c] = (u8)(pk2 & 0xff);
      pbuf[wid][g * 4 + r][16 + c] = (u8)((pk2 >> 8) & 0xff);
    }
    long af = *(const long*)(&pbuf[wid][c][g * 8]);
    const u8* et = &etls[cur][0];
#pragma unroll
    for (int n = 0; n < 32; ++n) {
      long bv = *(const long*)(et + n * 512 + pvb);
      eh[n] = __builtin_amdgcn_mfma_f32_16x16x32_fp8_fp8(af, bv, eh[n], 0, 0, 0);
    }
    __syncthreads();
  }

  // partial outputs: l (reduced over c), m, O (bf16)
#pragma unroll
  for (int r = 0; r < 4; ++r) {
    float tls = lsum[r];
    tls += __shfl_xor(tls, 1); tls += __shfl_xor(tls, 2);
    tls += __shfl_xor(tls, 4); tls += __shfl_xor(tls, 8);
    lsum[r] = tls;
  }
  u16* OP = Opart + (size_t)h * ((size_t)NROW * D_N);
#pragma unroll
  for (int r = 0; r < 4; ++r) {
    int brow = b * T_N + row0 + g * 4 + r;
    u16* orow = OP + (size_t)brow * D_N + c;
#pragma unroll
    for (int n = 0; n < 32; ++n) orow[n * 16] = f2bf16(eh[n][r]);
  }
  if (c == 0) {
#pragma unroll
    for (int r = 0; r < 4; ++r) {
      int brow = b * T_N + row0 + g * 4 + r;
      Mpart[h * NROW + brow] = mrun[r];
      Lpart[h * NROW + brow] = lsum[r];
    }
  }
}

// ---------------- k3: merge halves + cosine per row ----------------
__global__ void kcomb(const float* __restrict__ pred, const u16* __restrict__ Opart,
                      const float* __restrict__ Mpart, const float* __restrict__ Lpart,
                      float* __restrict__ rowloss, float* __restrict__ wrow) {
  int tr = threadIdx.x;
  int row = blockIdx.x * 8 + (tr >> 5);
  int ln = tr & 31;
  float m0 = Mpart[row], m1 = Mpart[NROW + row];
  float l0 = Lpart[row], l1 = Lpart[NROW + row];
  float m = fmaxf(m0, m1);
  float s0 = __expf(m0 - m), s1 = __expf(m1 - m);
  float l = s0 * l0 + s1 * l1;
  const float* pr = pred + (size_t)row * D_N + ln * 16;
  const u16* o0 = Opart + (size_t)row * D_N + ln * 16;
  const u16* o1 = o0 + (size_t)NROW * D_N;
  float dot = 0.f, e2 = 0.f, pn2 = 0.f;
#pragma unroll
  for (int q = 0; q < 2; ++q) {
    uint4 a0 = *(const uint4*)(o0 + q * 8);
    uint4 a1 = *(const uint4*)(o1 + q * 8);
    u32 w0[4] = {a0.x, a0.y, a0.z, a0.w};
    u32 w1[4] = {a1.x, a1.y, a1.z, a1.w};
    float4 p0 = *(const float4*)(pr + q * 8);
    float4 p1 = *(const float4*)(pr + q * 8 + 4);
    float pp[8] = {p0.x, p0.y, p0.z, p0.w, p1.x, p1.y, p1.z, p1.w};
#pragma unroll
    for (int j = 0; j < 8; ++j) {
      float f0 = bf2f((u16)((w0[j >> 1] >> ((j & 1) * 16)) & 0xffff));
      float f1 = bf2f((u16)((w1[j >> 1] >> ((j & 1) * 16)) & 0xffff));
      float ev = f0 * s0 + f1 * s1;
      dot += pp[j] * ev;
      e2 += ev * ev;
      pn2 += pp[j] * pp[j];
    }
  }
#pragma unroll
  for (int msk = 16; msk >= 1; msk >>= 1) {
    dot += __shfl_xor(dot, msk);
    e2 += __shfl_xor(e2, msk);
    pn2 += __shfl_xor(pn2, msk);
  }
  if (ln == 0) {
    float w = (l > 0.f) ? 1.f : 0.f;
    float pn = fmaxf(sqrtf(pn2), 1e-12f);
    float denom = pn * fmaxf(sqrtf(e2), 1e-8f * l);
    float cosv = (l > 0.f) ? dot / denom : 0.f;
    rowloss[row] = w * (1.f - cosv);
    wrow[row] = w;
  }
}

// ---------------- k4: deterministic final reduction ----------------
__global__ void kreduce(const float* __restrict__ rowloss, const float* __restrict__ wrow,
                        float* __restrict__ out) {
  __shared__ float sm[256], sw[256];
  float s = 0.f, w = 0.f;
  for (int i = threadIdx.x; i < NROW; i += 256) { s += rowloss[i]; w += wrow[i]; }
  sm[threadIdx.x] = s; sw[threadIdx.x] = w;
  __syncthreads();
#pragma unroll
  for (int st = 128; st >= 1; st >>= 1) {
    if ((int)threadIdx.x < st) {
      sm[threadIdx.x] += sm[threadIdx.x + st];
      sw[threadIdx.x] += sw[threadIdx.x + st];
    }
    __syncthreads();
  }
  if (threadIdx.x == 0) {
    float cnt = sw[0];
    float loss = (cnt > 0.f) ? sm[0] / fmaxf(cnt, 1.f) : 0.f;
    out[0] = loss;
    out[1] = (cnt > 0.f) ? 1.f - loss : 0.f;
  }
}

extern "C" void kernel_launch(void* const* d_in, const int* in_sizes, int n_in,
                              void* d_out, int out_size, void* d_ws, size_t ws_size,
                              hipStream_t stream) {
  const float* pred = (const float*)d_in[0];
  const float* text = (const float*)d_in[1];
  const int* mask = (const int*)d_in[2];
  char* ws = (char*)d_ws;
  const size_t EB8 = (size_t)B_N * T_N * D_N;          // 8MB per fp8 tensor
  const size_t OB = (size_t)NROW * D_N * 2;            // 16MB per bf16 O-half
  u8* EF = (u8*)ws;
  u8* ET = (u8*)(ws + EB8);
  u16* Opart = (u16*)(ws + 2 * EB8);                   // 2 halves = 32MB
  float* Mpart = (float*)(ws + 2 * EB8 + 2 * OB);      // 2*64KB
  float* Lpart = (float*)(ws + 2 * EB8 + 2 * OB + 131072);
  float* rowloss = (float*)(ws + 2 * EB8 + 2 * OB + 262144);
  float* wrow = (float*)(ws + 2 * EB8 + 2 * OB + 327680);
  float* out = (float*)d_out;

  kprep<<<dim3(64, 8), dim3(256), 0, stream>>>(text, EF, ET);
  kflash<<<dim3(512), dim3(256), 0, stream>>>(pred, EF, ET, mask, Opart, Mpart, Lpart);
  kcomb<<<dim3(NROW / 8), dim3(256), 0, stream>>>(pred, Opart, Mpart, Lpart, rowloss, wrow);
  kreduce<<<dim3(1), dim3(256), 0, stream>>>(rowloss, wrow, out);
}

// Round 6
// 120.535 us; speedup vs baseline: 4.5459x; 1.1851x over previous
//
#include <hip/hip_runtime.h>
#include <cstdint>

typedef float f32x4 __attribute__((ext_vector_type(4)));
typedef long longx2 __attribute__((ext_vector_type(2)));
typedef unsigned char u8;
typedef unsigned short u16;
typedef unsigned int u32;
typedef unsigned long long u64;

#define B_N 8
#define T_N 2048
#define D_N 512
#define TAU 5.0f
#define NROW (B_N * T_N)    // 16384

__device__ __forceinline__ void gload_lds16(const u8* g, u8* l) {
  __builtin_amdgcn_global_load_lds(
      (const __attribute__((address_space(1))) u32*)g,
      (__attribute__((address_space(3))) u32*)l, 16, 0, 0);
}

// pack 4 floats -> 4 fp8(e4m3) bytes in a u32
__device__ __forceinline__ u32 pk4_fp8(float a, float b, float c, float d) {
  int w = __builtin_amdgcn_cvt_pk_fp8_f32(a, b, 0, 0);
  w = __builtin_amdgcn_cvt_pk_fp8_f32(c, d, w, 1);
  return (u32)w;
}

__device__ __forceinline__ u16 f2bf16(float x) {   // RNE f32->bf16
  u32 u = __builtin_bit_cast(u32, x);
  u32 r = u + 0x7fffu + ((u >> 16) & 1u);
  return (u16)(r >> 16);
}
__device__ __forceinline__ float bf2f(u16 v) {
  u32 u = ((u32)v) << 16;
  return __builtin_bit_cast(float, u);
}

// ---------------- k1: normalize E rows, emit fp8 in b128-PAIR fragment order.
// EF2: addr = j*2048 + tok*64 + g*16 + h*8 + e -> E[tok][(2j+h)*32 + g*8 + e]
//      (j in 0..7: kk-pair index; 16KB per 32-token tile)
// ET2: addr = m*1024 + g*256 + c*16  + h*8 + e -> E[g*8+e][(2m+h)*16 + c]
//      (m in 0..15: n-pair index; one pair-block = 4*16*16B = 1024B; 16KB/tile)
__global__ void kprep(const float* __restrict__ text,
                      u8* __restrict__ EF, u8* __restrict__ ET) {
  __shared__ u8 tile[32][528];
  int b = blockIdx.y, t = blockIdx.x;
  int tr = threadIdx.x;
  int row = tr >> 3, seg = tr & 7;          // 32 rows x 8 segs of 64 d
  const float* src = text + ((size_t)b * T_N + t * 32 + row) * D_N + seg * 64;
  float4 v[16];
  float ss = 0.f;
#pragma unroll
  for (int j = 0; j < 16; ++j) {
    v[j] = *(const float4*)(src + j * 4);
    ss += v[j].x*v[j].x + v[j].y*v[j].y + v[j].z*v[j].z + v[j].w*v[j].w;
  }
  ss += __shfl_xor(ss, 1); ss += __shfl_xor(ss, 2); ss += __shfl_xor(ss, 4);
  float inv = 1.f / fmaxf(sqrtf(ss), 1e-12f);
  u32 w[16];
#pragma unroll
  for (int j = 0; j < 16; ++j)
    w[j] = pk4_fp8(v[j].x*inv, v[j].y*inv, v[j].z*inv, v[j].w*inv);
  uint4* ldst = (uint4*)&tile[row][seg * 64];
#pragma unroll
  for (int j = 0; j < 4; ++j)
    ldst[j] = make_uint4(w[4*j], w[4*j+1], w[4*j+2], w[4*j+3]);
  __syncthreads();
  size_t tbase = ((size_t)(b * 64 + t)) << 14;
  {
    // EF2: thread covers 64B: j = tr>>5, tok = tr&31
    int j = tr >> 5, tok = tr & 31;
    u32 acc[16];
#pragma unroll
    for (int g2 = 0; g2 < 4; ++g2)
#pragma unroll
      for (int h = 0; h < 2; ++h) {
        uint2 vv = *(const uint2*)&tile[tok][j*64 + h*32 + g2*8];
        acc[g2*4 + h*2] = vv.x; acc[g2*4 + h*2 + 1] = vv.y;
      }
    uint4* dst = (uint4*)(EF + tbase + tr * 64);
#pragma unroll
    for (int q = 0; q < 4; ++q)
      dst[q] = make_uint4(acc[4*q], acc[4*q+1], acc[4*q+2], acc[4*q+3]);
  }
  {
    // ET2: thread covers 64B: m = tr>>4, g = (tr>>2)&3, c0 = (tr&3)*4
    int m = tr >> 4, g2 = (tr >> 2) & 3, c0 = (tr & 3) * 4;
    u32 acc[16];
#pragma unroll
    for (int ci = 0; ci < 4; ++ci)
#pragma unroll
      for (int h = 0; h < 2; ++h) {
        int c = c0 + ci, n = 2*m + h;
        u32 lo = 0, hi = 0;
#pragma unroll
        for (int e = 0; e < 4; ++e) lo |= (u32)tile[g2*8 + e][n*16 + c] << (8*e);
#pragma unroll
        for (int e = 0; e < 4; ++e) hi |= (u32)tile[g2*8 + 4 + e][n*16 + c] << (8*e);
        acc[ci*4 + h*2] = lo; acc[ci*4 + h*2 + 1] = hi;
      }
    uint4* dst = (uint4*)(ET + tbase + tr * 64);
#pragma unroll
    for (int q = 0; q < 4; ++q)
      dst[q] = make_uint4(acc[4*q], acc[4*q+1], acc[4*q+2], acc[4*q+3]);
  }
}

// ---------------- k2: flash attention over a column HALF, FIXED-MAX softmax.
// cos is invariant to uniform p-scale, and |S|<=~1.06 bounds logits by TAU:
// p = exp(TAU*s - 1)  (max ~e^4.3=74 < fp8 max 448). No running max, no
// shuffle trees, no rescale pass, no Mpart. ----
__launch_bounds__(256, 2)
__global__ void kflash(const float* __restrict__ pred,
                       const u8* __restrict__ EF, const u8* __restrict__ ET,
                       const int* __restrict__ mask,
                       u16* __restrict__ Opart, float* __restrict__ Lpart) {
  int b = blockIdx.x & 7;                 // batch -> XCD pin
  int rem = blockIdx.x >> 3;
  int rb = rem & 31, h = rem >> 5;        // row-block, column half
  int wid = threadIdx.x >> 6, lane = threadIdx.x & 63;
  int g = lane >> 4, c = lane & 15;
  int row0 = rb * 64 + wid * 16;
  int t0 = h * 32;

  __shared__ u64 mbits[32];
  __shared__ __align__(16) u8 pbuf[4][16][40];
  __shared__ __align__(16) u8 els[2][16384];
  __shared__ __align__(16) u8 etls[2][16384];

  const u8* EFb = EF + (((size_t)(b * 64)) << 14) + (lane << 4);
  const u8* ETb = ET + (((size_t)(b * 64)) << 14) + (lane << 4);

  auto stage = [&](int buf, int t) {
    size_t tb = ((size_t)t) << 14;
#pragma unroll
    for (int j = 0; j < 4; ++j) {
      int ch = j * 4 + wid;
      gload_lds16(EFb + tb + (ch << 10), &els[buf][ch << 10]);
    }
#pragma unroll
    for (int j = 0; j < 4; ++j) {
      int ch = j * 4 + wid;
      gload_lds16(ETb + tb + (ch << 10), &etls[buf][ch << 10]);
    }
  };

  for (int chunk = wid; chunk < 32; chunk += 4) {
    int col = chunk * 64 + lane;
    u64 bal = __ballot(mask[b * T_N + col] == 0);  // True mask = PAD
    if (lane == 0) mbits[chunk] = bal;
  }

  stage(0, t0);

  // P fragments: two-pass fp32 normalize -> fp8; overlaps tile-0 staging.
  long pf[16];
  {
    int prow = row0 + c;
    const float* pr = pred + ((size_t)(b * T_N) + prow) * D_N;
    float ss = 0.f;
#pragma unroll
    for (int kk = 0; kk < 16; ++kk) {
      float4 v0 = *(const float4*)(pr + kk * 32 + g * 8);
      float4 v1 = *(const float4*)(pr + kk * 32 + g * 8 + 4);
      ss += v0.x*v0.x + v0.y*v0.y + v0.z*v0.z + v0.w*v0.w
          + v1.x*v1.x + v1.y*v1.y + v1.z*v1.z + v1.w*v1.w;
    }
    ss += __shfl_xor(ss, 16);
    ss += __shfl_xor(ss, 32);
    float inv = 1.f / fmaxf(sqrtf(ss), 1e-12f);
#pragma unroll
    for (int kk = 0; kk < 16; ++kk) {
      float4 v0 = *(const float4*)(pr + kk * 32 + g * 8);
      float4 v1 = *(const float4*)(pr + kk * 32 + g * 8 + 4);
      u32 lo = pk4_fp8(v0.x*inv, v0.y*inv, v0.z*inv, v0.w*inv);
      u32 hi = pk4_fp8(v1.x*inv, v1.y*inv, v1.z*inv, v1.w*inv);
      pf[kk] = (long)(((u64)hi << 32) | lo);
    }
  }

  __syncthreads();   // tile t0 staged; mbits visible

  f32x4 zero = {0.f, 0.f, 0.f, 0.f};
  f32x4 eh[32];
#pragma unroll
  for (int n = 0; n < 32; ++n) eh[n] = zero;
  float lsum[4] = {0.f, 0.f, 0.f, 0.f};

  const int sb_off = c * 64 + g * 16;     // S-phase b128 lane offset
  const int pv_off = g * 256 + c * 16;    // PV-phase b128 lane offset

#pragma unroll 1
  for (int tt = 0; tt < 32; ++tt) {
    int t = t0 + tt;
    int cur = tt & 1;
    if (tt + 1 < 32) stage(cur ^ 1, t + 1);   // issue-early
    int c0 = t * 32;

    // S = P . E^T : b128 pair reads, 4 independent chains of 8
    f32x4 sa0 = zero, sb0 = zero, sa1 = zero, sb1 = zero;
    const u8* el = &els[cur][0];
    __builtin_amdgcn_s_setprio(1);
#pragma unroll
    for (int j = 0; j < 8; ++j) {
      longx2 b0 = *(const longx2*)(el + j * 2048 + sb_off);
      longx2 b1 = *(const longx2*)(el + j * 2048 + 1024 + sb_off);
      sa0 = __builtin_amdgcn_mfma_f32_16x16x32_fp8_fp8(pf[2*j],   b0[0], sa0, 0, 0, 0);
      sb0 = __builtin_amdgcn_mfma_f32_16x16x32_fp8_fp8(pf[2*j+1], b0[1], sb0, 0, 0, 0);
      sa1 = __builtin_amdgcn_mfma_f32_16x16x32_fp8_fp8(pf[2*j],   b1[0], sa1, 0, 0, 0);
      sb1 = __builtin_amdgcn_mfma_f32_16x16x32_fp8_fp8(pf[2*j+1], b1[1], sb1, 0, 0, 0);
    }
    __builtin_amdgcn_s_setprio(0);
    f32x4 s0 = sa0 + sb0, s1 = sa1 + sb1;

    int col0 = c0 + c;
    bool v0 = (mbits[col0 >> 6] >> (col0 & 63)) & 1ULL;
    bool v1 = (mbits[(col0 + 16) >> 6] >> ((col0 + 16) & 63)) & 1ULL;
#pragma unroll
    for (int r = 0; r < 4; ++r) {
      float p0 = v0 ? __expf(TAU * s0[r] - 1.f) : 0.f;  // fixed-max softmax
      float p1 = v1 ? __expf(TAU * s1[r] - 1.f) : 0.f;
      lsum[r] += p0 + p1;
      u32 pk2 = (u32)__builtin_amdgcn_cvt_pk_fp8_f32(p0, p1, 0, 0);
      pbuf[wid][g * 4 + r][c] = (u8)(pk2 & 0xff);
      pbuf[wid][g * 4 + r][16 + c] = (u8)((pk2 >> 8) & 0xff);
    }
    long af = *(const long*)(&pbuf[wid][c][g * 8]);

    const u8* et = &etls[cur][0];
    __builtin_amdgcn_s_setprio(1);
#pragma unroll
    for (int m = 0; m < 16; ++m) {
      longx2 bv = *(const longx2*)(et + m * 1024 + pv_off);
      eh[2*m]   = __builtin_amdgcn_mfma_f32_16x16x32_fp8_fp8(af, bv[0], eh[2*m],   0, 0, 0);
      eh[2*m+1] = __builtin_amdgcn_mfma_f32_16x16x32_fp8_fp8(af, bv[1], eh[2*m+1], 0, 0, 0);
    }
    __builtin_amdgcn_s_setprio(0);
    __syncthreads();
  }

  // partial outputs: l (reduced over c), O (bf16)
#pragma unroll
  for (int r = 0; r < 4; ++r) {
    float tls = lsum[r];
    tls += __shfl_xor(tls, 1); tls += __shfl_xor(tls, 2);
    tls += __shfl_xor(tls, 4); tls += __shfl_xor(tls, 8);
    lsum[r] = tls;
  }
  u16* OP = Opart + (size_t)h * ((size_t)NROW * D_N);
#pragma unroll
  for (int r = 0; r < 4; ++r) {
    int brow = b * T_N + row0 + g * 4 + r;
    u16* orow = OP + (size_t)brow * D_N + c;
#pragma unroll
    for (int n = 0; n < 32; ++n) orow[n * 16] = f2bf16(eh[n][r]);
  }
  if (c == 0) {
#pragma unroll
    for (int r = 0; r < 4; ++r) {
      int brow = b * T_N + row0 + g * 4 + r;
      Lpart[h * NROW + brow] = lsum[r];
    }
  }
}

// ---------------- k3: merge halves (plain add: same fixed scale) + cosine ----
__global__ void kcomb(const float* __restrict__ pred, const u16* __restrict__ Opart,
                      const float* __restrict__ Lpart,
                      float* __restrict__ rowloss, float* __restrict__ wrow) {
  int tr = threadIdx.x;
  int row = blockIdx.x * 8 + (tr >> 5);
  int ln = tr & 31;
  float l = Lpart[row] + Lpart[NROW + row];
  const float* pr = pred + (size_t)row * D_N + ln * 16;
  const u16* o0 = Opart + (size_t)row * D_N + ln * 16;
  const u16* o1 = o0 + (size_t)NROW * D_N;
  float dot = 0.f, e2 = 0.f, pn2 = 0.f;
#pragma unroll
  for (int q = 0; q < 2; ++q) {
    uint4 a0 = *(const uint4*)(o0 + q * 8);
    uint4 a1 = *(const uint4*)(o1 + q * 8);
    u32 w0[4] = {a0.x, a0.y, a0.z, a0.w};
    u32 w1[4] = {a1.x, a1.y, a1.z, a1.w};
    float4 p0 = *(const float4*)(pr + q * 8);
    float4 p1 = *(const float4*)(pr + q * 8 + 4);
    float pp[8] = {p0.x, p0.y, p0.z, p0.w, p1.x, p1.y, p1.z, p1.w};
#pragma unroll
    for (int j = 0; j < 8; ++j) {
      float f0 = bf2f((u16)((w0[j >> 1] >> ((j & 1) * 16)) & 0xffff));
      float f1 = bf2f((u16)((w1[j >> 1] >> ((j & 1) * 16)) & 0xffff));
      float ev = f0 + f1;
      dot += pp[j] * ev;
      e2 += ev * ev;
      pn2 += pp[j] * pp[j];
    }
  }
#pragma unroll
  for (int msk = 16; msk >= 1; msk >>= 1) {
    dot += __shfl_xor(dot, msk);
    e2 += __shfl_xor(e2, msk);
    pn2 += __shfl_xor(pn2, msk);
  }
  if (ln == 0) {
    float w = (l > 0.f) ? 1.f : 0.f;
    float pn = fmaxf(sqrtf(pn2), 1e-12f);
    float denom = pn * fmaxf(sqrtf(e2), 1e-8f * l);
    float cosv = (l > 0.f) ? dot / denom : 0.f;
    rowloss[row] = w * (1.f - cosv);
    wrow[row] = w;
  }
}

// ---------------- k4: deterministic final reduction ----------------
__global__ void kreduce(const float* __restrict__ rowloss, const float* __restrict__ wrow,
                        float* __restrict__ out) {
  __shared__ float sm[256], sw[256];
  float s = 0.f, w = 0.f;
  for (int i = threadIdx.x; i < NROW; i += 256) { s += rowloss[i]; w += wrow[i]; }
  sm[threadIdx.x] = s; sw[threadIdx.x] = w;
  __syncthreads();
#pragma unroll
  for (int st = 128; st >= 1; st >>= 1) {
    if ((int)threadIdx.x < st) {
      sm[threadIdx.x] += sm[threadIdx.x + st];
      sw[threadIdx.x] += sw[threadIdx.x + st];
    }
    __syncthreads();
  }
  if (threadIdx.x == 0) {
    float cnt = sw[0];
    float loss = (cnt > 0.f) ? sm[0] / fmaxf(cnt, 1.f) : 0.f;
    out[0] = loss;
    out[1] = (cnt > 0.f) ? 1.f - loss : 0.f;
  }
}

extern "C" void kernel_launch(void* const* d_in, const int* in_sizes, int n_in,
                              void* d_out, int out_size, void* d_ws, size_t ws_size,
                              hipStream_t stream) {
  const float* pred = (const float*)d_in[0];
  const float* text = (const float*)d_in[1];
  const int* mask = (const int*)d_in[2];
  char* ws = (char*)d_ws;
  const size_t EB8 = (size_t)B_N * T_N * D_N;          // 8MB per fp8 tensor
  const size_t OB = (size_t)NROW * D_N * 2;            // 16MB per bf16 O-half
  u8* EF = (u8*)ws;
  u8* ET = (u8*)(ws + EB8);
  u16* Opart = (u16*)(ws + 2 * EB8);                   // 2 halves = 32MB
  float* Lpart = (float*)(ws + 2 * EB8 + 2 * OB);      // 2*64KB
  float* rowloss = (float*)(ws + 2 * EB8 + 2 * OB + 131072);
  float* wrow = (float*)(ws + 2 * EB8 + 2 * OB + 196608);
  float* out = (float*)d_out;

  kprep<<<dim3(64, 8), dim3(256), 0, stream>>>(text, EF, ET);
  kflash<<<dim3(512), dim3(256), 0, stream>>>(pred, EF, ET, mask, Opart, Lpart);
  kcomb<<<dim3(NROW / 8), dim3(256), 0, stream>>>(pred, Opart, Lpart, rowloss, wrow);
  kreduce<<<dim3(1), dim3(256), 0, stream>>>(rowloss, wrow, out);
}

// Round 7
// 105.601 us; speedup vs baseline: 5.1887x; 1.1414x over previous
//
#include <hip/hip_runtime.h>
#include <cstdint>

typedef float f32x4 __attribute__((ext_vector_type(4)));
typedef long longx2 __attribute__((ext_vector_type(2)));
typedef unsigned char u8;
typedef unsigned short u16;
typedef unsigned int u32;
typedef unsigned long long u64;

#define B_N 8
#define T_N 2048
#define D_N 512
#define TAU 5.0f
#define NROW (B_N * T_N)    // 16384
// exp(TAU*s - 1) == exp2(K1*s - K2)
#define K1E 7.213475204444817f
#define K2E 1.4426950408889634f

__device__ __forceinline__ void gload_lds16(const u8* g, u8* l) {
  __builtin_amdgcn_global_load_lds(
      (const __attribute__((address_space(1))) u32*)g,
      (__attribute__((address_space(3))) u32*)l, 16, 0, 0);
}

// pack 4 floats -> 4 fp8(e4m3) bytes in a u32
__device__ __forceinline__ u32 pk4_fp8(float a, float b, float c, float d) {
  int w = __builtin_amdgcn_cvt_pk_fp8_f32(a, b, 0, 0);
  w = __builtin_amdgcn_cvt_pk_fp8_f32(c, d, w, 1);
  return (u32)w;
}

__device__ __forceinline__ u16 f2bf16(float x) {   // RNE f32->bf16
  u32 u = __builtin_bit_cast(u32, x);
  u32 r = u + 0x7fffu + ((u >> 16) & 1u);
  return (u16)(r >> 16);
}
__device__ __forceinline__ float bf2f(u16 v) {
  u32 u = ((u32)v) << 16;
  return __builtin_bit_cast(float, u);
}

// ---------------- k1: normalize E rows, emit fp8 in b128-PAIR fragment order.
// EF2: addr = j*2048 + tok*64 + g*16 + h*8 + e -> E[tok][(2j+h)*32 + g*8 + e]
// ET2: addr = m*1024 + g*256 + c*16  + h*8 + e -> E[g*8+e][(2m+h)*16 + c]
__global__ void kprep(const float* __restrict__ text,
                      u8* __restrict__ EF, u8* __restrict__ ET) {
  __shared__ u8 tile[32][528];
  int b = blockIdx.y, t = blockIdx.x;
  int tr = threadIdx.x;
  int row = tr >> 3, seg = tr & 7;          // 32 rows x 8 segs of 64 d
  const float* src = text + ((size_t)b * T_N + t * 32 + row) * D_N + seg * 64;
  float4 v[16];
  float ss = 0.f;
#pragma unroll
  for (int j = 0; j < 16; ++j) {
    v[j] = *(const float4*)(src + j * 4);
    ss += v[j].x*v[j].x + v[j].y*v[j].y + v[j].z*v[j].z + v[j].w*v[j].w;
  }
  ss += __shfl_xor(ss, 1); ss += __shfl_xor(ss, 2); ss += __shfl_xor(ss, 4);
  float inv = 1.f / fmaxf(sqrtf(ss), 1e-12f);
  u32 w[16];
#pragma unroll
  for (int j = 0; j < 16; ++j)
    w[j] = pk4_fp8(v[j].x*inv, v[j].y*inv, v[j].z*inv, v[j].w*inv);
  uint4* ldst = (uint4*)&tile[row][seg * 64];
#pragma unroll
  for (int j = 0; j < 4; ++j)
    ldst[j] = make_uint4(w[4*j], w[4*j+1], w[4*j+2], w[4*j+3]);
  __syncthreads();
  size_t tbase = ((size_t)(b * 64 + t)) << 14;
  {
    // EF2: thread covers 64B: j = tr>>5, tok = tr&31
    int j = tr >> 5, tok = tr & 31;
    u32 acc[16];
#pragma unroll
    for (int g2 = 0; g2 < 4; ++g2)
#pragma unroll
      for (int h = 0; h < 2; ++h) {
        uint2 vv = *(const uint2*)&tile[tok][j*64 + h*32 + g2*8];
        acc[g2*4 + h*2] = vv.x; acc[g2*4 + h*2 + 1] = vv.y;
      }
    uint4* dst = (uint4*)(EF + tbase + tr * 64);
#pragma unroll
    for (int q = 0; q < 4; ++q)
      dst[q] = make_uint4(acc[4*q], acc[4*q+1], acc[4*q+2], acc[4*q+3]);
  }
  {
    // ET2: thread covers 64B: m = tr>>4, g = (tr>>2)&3, c0 = (tr&3)*4
    int m = tr >> 4, g2 = (tr >> 2) & 3, c0 = (tr & 3) * 4;
    u32 acc[16];
#pragma unroll
    for (int ci = 0; ci < 4; ++ci)
#pragma unroll
      for (int h = 0; h < 2; ++h) {
        int c = c0 + ci, n = 2*m + h;
        u32 lo = 0, hi = 0;
#pragma unroll
        for (int e = 0; e < 4; ++e) lo |= (u32)tile[g2*8 + e][n*16 + c] << (8*e);
#pragma unroll
        for (int e = 0; e < 4; ++e) hi |= (u32)tile[g2*8 + 4 + e][n*16 + c] << (8*e);
        acc[ci*4 + h*2] = lo; acc[ci*4 + h*2 + 1] = hi;
      }
    uint4* dst = (uint4*)(ET + tbase + tr * 64);
#pragma unroll
    for (int q = 0; q < 4; ++q)
      dst[q] = make_uint4(acc[4*q], acc[4*q+1], acc[4*q+2], acc[4*q+3]);
  }
}

// ---------------- k2: flash attention over a column HALF, FIXED-MAX softmax,
// operand-swapped S (S^T = mfma(E,P)) so P-weights land row-local per lane:
// softmax->PV relayout = 4 shfl + 2 selects, NO LDS bounce. ----
__launch_bounds__(256, 2)
__global__ void kflash(const float* __restrict__ pred,
                       const u8* __restrict__ EF, const u8* __restrict__ ET,
                       const int* __restrict__ mask,
                       u16* __restrict__ Opart, float* __restrict__ Lpart) {
  int b = blockIdx.x & 7;                 // batch -> XCD pin
  int rem = blockIdx.x >> 3;
  int rb = rem & 31, h = rem >> 5;        // row-block, column half
  int wid = threadIdx.x >> 6, lane = threadIdx.x & 63;
  int g = lane >> 4, c = lane & 15;
  int row0 = rb * 64 + wid * 16;
  int t0 = h * 32;

  __shared__ u64 mbits[32];
  __shared__ __align__(16) u8 els[2][16384];
  __shared__ __align__(16) u8 etls[2][16384];

  const u8* EFb = EF + (((size_t)(b * 64)) << 14) + (lane << 4);
  const u8* ETb = ET + (((size_t)(b * 64)) << 14) + (lane << 4);

  auto stage = [&](int buf, int t) {
    size_t tb = ((size_t)t) << 14;
#pragma unroll
    for (int j = 0; j < 4; ++j) {
      int ch = j * 4 + wid;
      gload_lds16(EFb + tb + (ch << 10), &els[buf][ch << 10]);
    }
#pragma unroll
    for (int j = 0; j < 4; ++j) {
      int ch = j * 4 + wid;
      gload_lds16(ETb + tb + (ch << 10), &etls[buf][ch << 10]);
    }
  };

  for (int chunk = wid; chunk < 32; chunk += 4) {
    int col = chunk * 64 + lane;
    u64 bal = __ballot(mask[b * T_N + col] == 0);  // True mask = PAD
    if (lane == 0) mbits[chunk] = bal;
  }

  stage(0, t0);

  // P fragments: two-pass fp32 normalize -> fp8; overlaps tile-0 staging.
  long pf[16];
  {
    int prow = row0 + c;
    const float* pr = pred + ((size_t)(b * T_N) + prow) * D_N;
    float ss = 0.f;
#pragma unroll
    for (int kk = 0; kk < 16; ++kk) {
      float4 v0 = *(const float4*)(pr + kk * 32 + g * 8);
      float4 v1 = *(const float4*)(pr + kk * 32 + g * 8 + 4);
      ss += v0.x*v0.x + v0.y*v0.y + v0.z*v0.z + v0.w*v0.w
          + v1.x*v1.x + v1.y*v1.y + v1.z*v1.z + v1.w*v1.w;
    }
    ss += __shfl_xor(ss, 16);
    ss += __shfl_xor(ss, 32);
    float inv = 1.f / fmaxf(sqrtf(ss), 1e-12f);
#pragma unroll
    for (int kk = 0; kk < 16; ++kk) {
      float4 v0 = *(const float4*)(pr + kk * 32 + g * 8);
      float4 v1 = *(const float4*)(pr + kk * 32 + g * 8 + 4);
      u32 lo = pk4_fp8(v0.x*inv, v0.y*inv, v0.z*inv, v0.w*inv);
      u32 hi = pk4_fp8(v1.x*inv, v1.y*inv, v1.z*inv, v1.w*inv);
      pf[kk] = (long)(((u64)hi << 32) | lo);
    }
  }

  __syncthreads();   // tile t0 staged; mbits visible

  f32x4 zero = {0.f, 0.f, 0.f, 0.f};
  f32x4 eh[32];
#pragma unroll
  for (int n = 0; n < 32; ++n) eh[n] = zero;
  float lsum = 0.f;                        // per-lane: q-row c partial

  const int sb_off = c * 64 + g * 16;      // S-phase A-frag lane offset
  const int pv_off = g * 256 + c * 16;     // PV-phase B-frag lane offset
  const int a0 = (((g << 1) & 3) << 4) + c;  // exchange src lanes
  const int a1 = a0 + 16;

#pragma unroll 1
  for (int tt = 0; tt < 32; ++tt) {
    int t = t0 + tt;
    int cur = tt & 1;
    if (tt + 1 < 32) stage(cur ^ 1, t + 1);   // issue-early
    int c0 = t * 32;

    // S^T = E . P^T : A = E-frag (toks), B = pf. Same LDS reads as before.
    f32x4 ta0 = zero, tb0 = zero, ta1 = zero, tb1 = zero;
    const u8* el = &els[cur][0];
    __builtin_amdgcn_s_setprio(1);
#pragma unroll
    for (int j = 0; j < 8; ++j) {
      longx2 b0 = *(const longx2*)(el + j * 2048 + sb_off);
      longx2 b1 = *(const longx2*)(el + j * 2048 + 1024 + sb_off);
      ta0 = __builtin_amdgcn_mfma_f32_16x16x32_fp8_fp8(b0[0], pf[2*j],   ta0, 0, 0, 0);
      tb0 = __builtin_amdgcn_mfma_f32_16x16x32_fp8_fp8(b0[1], pf[2*j+1], tb0, 0, 0, 0);
      ta1 = __builtin_amdgcn_mfma_f32_16x16x32_fp8_fp8(b1[0], pf[2*j],   ta1, 0, 0, 0);
      tb1 = __builtin_amdgcn_mfma_f32_16x16x32_fp8_fp8(b1[1], pf[2*j+1], tb1, 0, 0, 0);
    }
    __builtin_amdgcn_s_setprio(0);
    f32x4 st0 = ta0 + tb0, st1 = ta1 + tb1;  // st0: toks g*4+r, st1: 16+g*4+r (qrow c)

    // masks: 4 consecutive toks per half, same 64-bit word (c0 mult of 32)
    u64 mw = mbits[c0 >> 6];
    u32 sh0 = (c0 & 63) + g * 4;
    u32 bits0 = (u32)(mw >> sh0) & 0xf;
    u32 bits1 = (u32)(mw >> (sh0 + 16)) & 0xf;
    float p0[4], p1[4];
#pragma unroll
    for (int r = 0; r < 4; ++r) {
      p0[r] = (bits0 >> r) & 1 ? __builtin_exp2f(fmaf(K1E, st0[r], -K2E)) : 0.f;
      p1[r] = (bits1 >> r) & 1 ? __builtin_exp2f(fmaf(K1E, st1[r], -K2E)) : 0.f;
      lsum += p0[r] + p1[r];
    }
    u32 lo = pk4_fp8(p0[0], p0[1], p0[2], p0[3]);  // toks g*4..+3
    u32 hi = pk4_fp8(p1[0], p1[1], p1[2], p1[3]);  // toks 16+g*4..+3

    // in-register transpose: af = P[row c][toks 8g..8g+7]
    u32 pl0 = (u32)__shfl((int)lo, a0); u32 ph0 = (u32)__shfl((int)hi, a0);
    u32 pl1 = (u32)__shfl((int)lo, a1); u32 ph1 = (u32)__shfl((int)hi, a1);
    u32 w0 = (g < 2) ? pl0 : ph0;
    u32 w1 = (g < 2) ? pl1 : ph1;
    long af = (long)(((u64)w1 << 32) | w0);

    const u8* et = &etls[cur][0];
    __builtin_amdgcn_s_setprio(1);
#pragma unroll
    for (int m = 0; m < 16; ++m) {
      longx2 bv = *(const longx2*)(et + m * 1024 + pv_off);
      eh[2*m]   = __builtin_amdgcn_mfma_f32_16x16x32_fp8_fp8(af, bv[0], eh[2*m],   0, 0, 0);
      eh[2*m+1] = __builtin_amdgcn_mfma_f32_16x16x32_fp8_fp8(af, bv[1], eh[2*m+1], 0, 0, 0);
    }
    __builtin_amdgcn_s_setprio(0);
    __syncthreads();
  }

  // partial outputs: l (reduce over g-groups; row = c), O (bf16)
  lsum += __shfl_xor(lsum, 16);
  lsum += __shfl_xor(lsum, 32);
  u16* OP = Opart + (size_t)h * ((size_t)NROW * D_N);
#pragma unroll
  for (int r = 0; r < 4; ++r) {
    int brow = b * T_N + row0 + g * 4 + r;
    u16* orow = OP + (size_t)brow * D_N + c;
#pragma unroll
    for (int n = 0; n < 32; ++n) orow[n * 16] = f2bf16(eh[n][r]);
  }
  if (g == 0) {
    Lpart[h * NROW + b * T_N + row0 + c] = lsum;
  }
}

// ---------------- k3: merge halves + cosine + per-block partial sums ----------------
__global__ void kcomb(const float* __restrict__ pred, const u16* __restrict__ Opart,
                      const float* __restrict__ Lpart,
                      float* __restrict__ pl, float* __restrict__ pw) {
  __shared__ float sl[8], swv[8];
  int tr = threadIdx.x;
  int row = blockIdx.x * 8 + (tr >> 5);
  int ln = tr & 31;
  float l = Lpart[row] + Lpart[NROW + row];
  const float* pr = pred + (size_t)row * D_N + ln * 16;
  const u16* o0 = Opart + (size_t)row * D_N + ln * 16;
  const u16* o1 = o0 + (size_t)NROW * D_N;
  float dot = 0.f, e2 = 0.f, pn2 = 0.f;
#pragma unroll
  for (int q = 0; q < 2; ++q) {
    uint4 a0 = *(const uint4*)(o0 + q * 8);
    uint4 a1 = *(const uint4*)(o1 + q * 8);
    u32 w0[4] = {a0.x, a0.y, a0.z, a0.w};
    u32 w1[4] = {a1.x, a1.y, a1.z, a1.w};
    float4 p0 = *(const float4*)(pr + q * 8);
    float4 p1 = *(const float4*)(pr + q * 8 + 4);
    float pp[8] = {p0.x, p0.y, p0.z, p0.w, p1.x, p1.y, p1.z, p1.w};
#pragma unroll
    for (int j = 0; j < 8; ++j) {
      float f0 = bf2f((u16)((w0[j >> 1] >> ((j & 1) * 16)) & 0xffff));
      float f1 = bf2f((u16)((w1[j >> 1] >> ((j & 1) * 16)) & 0xffff));
      float ev = f0 + f1;
      dot += pp[j] * ev;
      e2 += ev * ev;
      pn2 += pp[j] * pp[j];
    }
  }
#pragma unroll
  for (int msk = 16; msk >= 1; msk >>= 1) {
    dot += __shfl_xor(dot, msk);
    e2 += __shfl_xor(e2, msk);
    pn2 += __shfl_xor(pn2, msk);
  }
  if (ln == 0) {
    float w = (l > 0.f) ? 1.f : 0.f;
    float pn = fmaxf(sqrtf(pn2), 1e-12f);
    float denom = pn * fmaxf(sqrtf(e2), 1e-8f * l);
    float cosv = (l > 0.f) ? dot / denom : 0.f;
    sl[tr >> 5] = w * (1.f - cosv);
    swv[tr >> 5] = w;
  }
  __syncthreads();
  if (tr == 0) {
    float a = 0.f, b2 = 0.f;
#pragma unroll
    for (int i = 0; i < 8; ++i) { a += sl[i]; b2 += swv[i]; }
    pl[blockIdx.x] = a;
    pw[blockIdx.x] = b2;
  }
}

// ---------------- k4: deterministic final reduction (2048 partials) ----------------
__global__ void kreduce(const float* __restrict__ pl, const float* __restrict__ pw,
                        float* __restrict__ out) {
  __shared__ float sm[256], sw[256];
  float s = 0.f, w = 0.f;
  for (int i = threadIdx.x; i < NROW / 8; i += 256) { s += pl[i]; w += pw[i]; }
  sm[threadIdx.x] = s; sw[threadIdx.x] = w;
  __syncthreads();
#pragma unroll
  for (int st = 128; st >= 1; st >>= 1) {
    if ((int)threadIdx.x < st) {
      sm[threadIdx.x] += sm[threadIdx.x + st];
      sw[threadIdx.x] += sw[threadIdx.x + st];
    }
    __syncthreads();
  }
  if (threadIdx.x == 0) {
    float cnt = sw[0];
    float loss = (cnt > 0.f) ? sm[0] / fmaxf(cnt, 1.f) : 0.f;
    out[0] = loss;
    out[1] = (cnt > 0.f) ? 1.f - loss : 0.f;
  }
}

extern "C" void kernel_launch(void* const* d_in, const int* in_sizes, int n_in,
                              void* d_out, int out_size, void* d_ws, size_t ws_size,
                              hipStream_t stream) {
  const float* pred = (const float*)d_in[0];
  const float* text = (const float*)d_in[1];
  const int* mask = (const int*)d_in[2];
  char* ws = (char*)d_ws;
  const size_t EB8 = (size_t)B_N * T_N * D_N;          // 8MB per fp8 tensor
  const size_t OB = (size_t)NROW * D_N * 2;            // 16MB per bf16 O-half
  u8* EF = (u8*)ws;
  u8* ET = (u8*)(ws + EB8);
  u16* Opart = (u16*)(ws + 2 * EB8);                   // 2 halves = 32MB
  float* Lpart = (float*)(ws + 2 * EB8 + 2 * OB);      // 2*64KB
  float* pl = (float*)(ws + 2 * EB8 + 2 * OB + 131072);
  float* pw = (float*)(ws + 2 * EB8 + 2 * OB + 131072 + 16384);
  float* out = (float*)d_out;

  kprep<<<dim3(64, 8), dim3(256), 0, stream>>>(text, EF, ET);
  kflash<<<dim3(512), dim3(256), 0, stream>>>(pred, EF, ET, mask, Opart, Lpart);
  kcomb<<<dim3(NROW / 8), dim3(256), 0, stream>>>(pred, Opart, Lpart, pl, pw);
  kreduce<<<dim3(1), dim3(256), 0, stream>>>(pl, pw, out);
}